// Round 9
// baseline (2106.839 us; speedup 1.0000x reference)
//
#include <hip/hip_runtime.h>
#include <hip/hip_bf16.h>

typedef __bf16 bf16_t;
typedef bf16_t bf16x8 __attribute__((ext_vector_type(8)));
typedef bf16_t bf16x4 __attribute__((ext_vector_type(4)));
typedef float  f32x4  __attribute__((ext_vector_type(4)));
typedef float  f32x16 __attribute__((ext_vector_type(16)));

#define NN   81
#define BB   512
#define BN   41472          // 512*81
#define EE   1620

// 4-bit XOR swizzle on the 16B granule index (node/prep kernels).
__device__ __forceinline__ int swz(int r, int k) {
    return (r << 7) + ((((k >> 3) ^ (r & 15)) << 3) | (k & 7));
}

// k_edge LDS layout: granule-plane-major with row-XOR.
// element offset of (row r, granule g=c>>3) = g*1024 + ((r ^ (g&7))*8).
// - GEMM A-reads: g uniform per half-wave, lm^c permutes 0..31 -> balanced,
//   and c=(2kk+h)&7 has only 4 distinct values -> 4 precomputed bases,
//   reads are ds_read_b128 base+imm (no per-read VALU; round-8's win).
// - Staging writes / agg reads: r fixed, g varies -> r^(g&7) spans 8 slots
//   -> exactly the 8-wrap minimum for 64x16B -> 0 conflict (fixes round-8's
//   16-way, SQ_LDS_BANK_CONFLICT 22.2M).
__device__ __forceinline__ int pmjx(int r, int g) {
    return (g << 10) + ((r ^ (g & 7)) << 3);
}

// 16x16x32 packed-weight offset (prep + node kernels)
__device__ __forceinline__ int wpack(int n, int k) {
    return ((n >> 6) << 13) + (((((k >> 5) << 2) + ((n >> 4) & 3))) << 9)
         + (((((k >> 3) & 3) << 4) + (n & 15)) << 3) + (k & 7);
}

// 32x32x16 packed-weight offset (edge kernel)
__device__ __forceinline__ int wpack32(int n, int k) {
    return ((((k >> 4) << 2) | (n >> 5)) << 9)
         + (((((k >> 3) & 1) << 5) | (n & 31)) << 3) + (k & 7);
}

// pack two f32 -> bf16x2, round-half-up: 2 adds + 1 v_perm
__device__ __forceinline__ unsigned pkbf(float lo, float hi) {
    unsigned a = __float_as_uint(lo) + 0x8000u;
    unsigned b = __float_as_uint(hi) + 0x8000u;
    return __builtin_amdgcn_perm(b, a, 0x07060302);
}

// truncating pack (1 v_perm) — intra-step activations only
__device__ __forceinline__ unsigned pkbf_t(float lo, float hi) {
    return __builtin_amdgcn_perm(__float_as_uint(hi), __float_as_uint(lo), 0x07060302);
}

__device__ __forceinline__ float bflo(unsigned d) { return __uint_as_float(d << 16); }
__device__ __forceinline__ float bfhi(unsigned d) { return __uint_as_float(d & 0xffff0000u); }

// relu(p+q) on packed bf16x2, all-f32 path (native v_max_f32)
__device__ __forceinline__ unsigned addrelu2(unsigned pd, unsigned qd) {
    float lo = fmaxf(bflo(pd) + bflo(qd), 0.f);
    float hi = fmaxf(bfhi(pd) + bfhi(qd), 0.f);
    return pkbf(lo, hi);
}

// ---------------- 16x16x32 GEMM (prep + node) ----------------
__device__ __forceinline__ void gemm128s(f32x4 (&acc)[4][4], const bf16_t* act,
                                         const bf16_t* __restrict__ Wp,
                                         int wm, int wn, int lane, int lrow, int q) {
    f32x4 z = {0.f, 0.f, 0.f, 0.f};
    #pragma unroll
    for (int i = 0; i < 4; i++)
        #pragma unroll
        for (int j = 0; j < 4; j++) acc[i][j] = z;
    const bf16_t* wbase = Wp + (wn << 13) + (lane << 3);
    #pragma unroll
    for (int k0 = 0; k0 < 128; k0 += 32) {
        bf16x8 af[4], wf[4];
        #pragma unroll
        for (int mt = 0; mt < 4; mt++)
            af[mt] = *(const bf16x8*)&act[swz(wm * 64 + mt * 16 + lrow, k0 + q * 8)];
        #pragma unroll
        for (int nt = 0; nt < 4; nt++)
            wf[nt] = *(const bf16x8*)(wbase + ((((k0 >> 5) << 2) + nt) << 9));
        #pragma unroll
        for (int nt = 0; nt < 4; nt++)
            #pragma unroll
            for (int mt = 0; mt < 4; mt++)
                acc[nt][mt] = __builtin_amdgcn_mfma_f32_16x16x32_bf16(wf[nt], af[mt], acc[nt][mt], 0, 0, 0);
    }
}

// ---------------- edge-kernel GEMM: wave tile M=MT*32 rows x N=32 cols ----------------
template<int MT>
__device__ __forceinline__ void gemm_e(f32x16 (&acc)[MT], const bf16_t* act,
                                       const bf16_t* __restrict__ W,
                                       const float* __restrict__ bias,
                                       int wid, int lane) {
    int lm = lane & 31, h = lane >> 5;
    #pragma unroll
    for (int gg = 0; gg < 4; gg++) {
        float4 b4 = *(const float4*)&bias[wid * 32 + 8 * gg + 4 * h];
        #pragma unroll
        for (int mt = 0; mt < MT; mt++) {
            acc[mt][4 * gg + 0] = b4.x; acc[mt][4 * gg + 1] = b4.y;
            acc[mt][4 * gg + 2] = b4.z; acc[mt][4 * gg + 3] = b4.w;
        }
    }
    const bf16_t* wl = W + (lane << 3);
    // granule for (kk,h) is 2kk+h; c = (2kk+h)&7 has 4 distinct values (kk&3).
    const bf16_t* al[4];
    #pragma unroll
    for (int j = 0; j < 4; j++)
        al[j] = act + (h << 10) + ((lm ^ ((2 * j + h) & 7)) << 3);
    #pragma unroll
    for (int kk = 0; kk < 8; kk++) {
        bf16x8 wf = *(const bf16x8*)(wl + (((kk << 2) + wid) << 9));
        #pragma unroll
        for (int mt = 0; mt < MT; mt++) {
            bf16x8 af = *(const bf16x8*)(al[kk & 3] + (kk << 11) + (mt << 8));
            acc[mt] = __builtin_amdgcn_mfma_f32_32x32x16_bf16(wf, af, acc[mt], 0, 0, 0);
        }
    }
}

// relu writeback: col block nb=32wid+8gg+4h lives in granule G=4wid+gg at
// byte offset 8h; row-XOR c = (4wid+gg)&7 = 4(wid&1)+gg -> 4 bases + imm.
template<int MT>
__device__ __forceinline__ void wb_e(bf16_t* act, f32x16 (&acc)[MT], int wid, int lane) {
    int lm = lane & 31, h = lane >> 5;
    bf16_t* wb[4];
    #pragma unroll
    for (int gg = 0; gg < 4; gg++)
        wb[gg] = act + ((4 * wid + gg) << 10) + ((lm ^ (4 * (wid & 1) + gg)) << 3) + (h << 2);
    #pragma unroll
    for (int mt = 0; mt < MT; mt++)
        #pragma unroll
        for (int gg = 0; gg < 4; gg++) {
            uint2 u;
            u.x = pkbf_t(fmaxf(acc[mt][4 * gg + 0], 0.f), fmaxf(acc[mt][4 * gg + 1], 0.f));
            u.y = pkbf_t(fmaxf(acc[mt][4 * gg + 2], 0.f), fmaxf(acc[mt][4 * gg + 3], 0.f));
            *(uint2*)(wb[gg] + (mt << 8)) = u;
        }
}

// ---------------- node-kernel GEMM: wave tile 32(M) x 32(N) ----------------
__device__ __forceinline__ void gemm32s(f32x4 (&acc)[2][2], const bf16_t* act,
                                        const bf16_t* __restrict__ Wp,
                                        int wid, int lane, int lrow, int q, bool zero) {
    if (zero) {
        f32x4 z = {0.f, 0.f, 0.f, 0.f};
        acc[0][0] = z; acc[0][1] = z; acc[1][0] = z; acc[1][1] = z;
    }
    int wn = wid >> 1, ntb = (wid & 1) << 1;
    const bf16_t* wbase = Wp + (wn << 13) + (lane << 3);
    #pragma unroll
    for (int k0 = 0; k0 < 128; k0 += 32) {
        bf16x8 af[2], wf[2];
        af[0] = *(const bf16x8*)&act[swz(lrow, k0 + q * 8)];
        af[1] = *(const bf16x8*)&act[swz(16 + lrow, k0 + q * 8)];
        wf[0] = *(const bf16x8*)(wbase + ((((k0 >> 5) << 2) + ntb) << 9));
        wf[1] = *(const bf16x8*)(wbase + ((((k0 >> 5) << 2) + ntb + 1) << 9));
        #pragma unroll
        for (int nt = 0; nt < 2; nt++)
            #pragma unroll
            for (int mt = 0; mt < 2; mt++)
                acc[nt][mt] = __builtin_amdgcn_mfma_f32_16x16x32_bf16(wf[nt], af[mt], acc[nt][mt], 0, 0, 0);
    }
}

__device__ __forceinline__ void wb32(bf16_t* act, f32x4 (&acc)[2][2], const float* __restrict__ bias,
                                     int colb, int lrow, int q) {
    #pragma unroll
    for (int nt = 0; nt < 2; nt++) {
        int nb = colb + nt * 16 + q * 4;
        float4 b4 = *(const float4*)&bias[nb];
        #pragma unroll
        for (int mt = 0; mt < 2; mt++) {
            int m = mt * 16 + lrow;
            uint2 u;
            u.x = pkbf_t(fmaxf(acc[nt][mt][0] + b4.x, 0.f), fmaxf(acc[nt][mt][1] + b4.y, 0.f));
            u.y = pkbf_t(fmaxf(acc[nt][mt][2] + b4.z, 0.f), fmaxf(acc[nt][mt][3] + b4.w, 0.f));
            *(uint2*)&act[swz(m, nb)] = u;
        }
    }
}

// ---------------- prep kernels ----------------

__global__ __launch_bounds__(256) void k_embed(const float* __restrict__ x, const float* __restrict__ W_in,
                                               const float* __restrict__ b_in, const float* __restrict__ pos,
                                               bf16_t* __restrict__ hb) {
    int idx = blockIdx.x * 256 + threadIdx.x;   // < BN*128
    int row = idx >> 7, col = idx & 127;
    int n = row % NN;
    const float* xr = x + (size_t)row * 10;
    float s = b_in[col] + pos[n * 128 + col];
    #pragma unroll
    for (int k = 0; k < 10; k++) s += xr[k] * W_in[k * 128 + col];
    hb[idx] = (bf16_t)s;
}

struct PackArgs { const float* s[9]; };

__global__ __launch_bounds__(256) void k_pack_all(PackArgs pa, bf16_t* __restrict__ dst) {
    const int slot[9] = {0, 1, 2, 3, 4, 6, 7, 8, 9};
    int idx = blockIdx.x * 256 + threadIdx.x;   // < 9*16384
    int w = idx >> 14, r = idx & 16383;
    int n = r >> 7, k = r & 127;
    int po = (w == 2 || w == 3) ? wpack32(n, k) : wpack(n, k);   // edge weights use 32x32 layout
    dst[slot[w] * 16384 + po] = (bf16_t)pa.s[w][k * 128 + n];
}

__global__ __launch_bounds__(256) void k_fuse(const float* __restrict__ mW3, const float* __restrict__ nW0,
                                              bf16_t* __restrict__ Ft) {
    int idx = blockIdx.x * 256 + threadIdx.x;   // < 16384
    int n = idx >> 7, k = idx & 127;
    float s = 0.f;
    for (int j = 0; j < 128; j++) s += mW3[k * 128 + j] * nW0[(256 + j) * 128 + n];
    Ft[wpack(n, k)] = (bf16_t)s;
}

__global__ __launch_bounds__(128) void k_bias(const float* __restrict__ nb0, const float* __restrict__ mb3,
                                              const float* __restrict__ nW0, float* __restrict__ bfix) {
    int n = threadIdx.x;
    float s = 0.f;
    for (int j = 0; j < 128; j++) s += mb3[j] * nW0[(256 + j) * 128 + n];
    bfix[n] = nb0[n] + 20.f * s;
}

// one launch does C2 (bf16, bias=bfix), P (bf16), Q' (bf16, bias=mb0); input hb is bf16
__global__ __launch_bounds__(256, 2) void k_simple3(const bf16_t* __restrict__ in,
                                                    const bf16_t* __restrict__ Wp,
                                                    const float* __restrict__ bfix,
                                                    const float* __restrict__ mb0,
                                                    bf16_t* __restrict__ C2b,
                                                    bf16_t* __restrict__ Pd,
                                                    bf16_t* __restrict__ Qd) {
    __shared__ __align__(16) bf16_t act[16384];
    int tid = threadIdx.x;
    int sel = blockIdx.x / 324, blk = blockIdx.x - sel * 324;
    size_t i0 = (size_t)blk * 128;
    int lane = tid & 63, wid = tid >> 6;
    int wm = wid >> 1, wn = wid & 1, lrow = lane & 15, q = lane >> 4;

    for (int ch = tid; ch < 2048; ch += 256) {      // raw bf16 stage
        int r = ch >> 4, p = ch & 15;
        *(uint4*)&act[swz(r, p << 3)] = *(const uint4*)(in + (i0 + r) * 128 + (p << 3));
    }
    __syncthreads();
    const bf16_t* W = Wp + (sel == 0 ? 9 * 16384 : (sel == 1 ? 0 : 16384));
    f32x4 acc[4][4];
    gemm128s(acc, act, W, wm, wn, lane, lrow, q);
    bf16_t* dst = (sel == 0) ? C2b : ((sel == 1) ? Pd : Qd);
    #pragma unroll
    for (int nt = 0; nt < 4; nt++) {
        int nb = wn * 64 + nt * 16 + q * 4;
        float4 b4 = (sel == 0) ? *(const float4*)&bfix[nb]
                  : (sel == 2) ? *(const float4*)&mb0[nb]
                               : make_float4(0.f, 0.f, 0.f, 0.f);
        #pragma unroll
        for (int mt = 0; mt < 4; mt++) {
            int m = wm * 64 + mt * 16 + lrow;
            uint2 u;
            u.x = pkbf(acc[nt][mt][0] + b4.x, acc[nt][mt][1] + b4.y);
            u.y = pkbf(acc[nt][mt][2] + b4.z, acc[nt][mt][3] + b4.w);
            *(uint2*)(dst + (i0 + m) * 128 + nb) = u;
        }
    }
}

// ---------------- edge kernel: 32x32x16 MFMA, M128xN32 wave tiles, XOR-plane-major LDS ----------------
// Grid (b=512, g=14) keeps each XCD's P/Q working set L2-resident (round-6:
// FETCH 42.7MB -> 10.7MB). Staging iteration order identical to round 6
// (16 consecutive lanes read 16 consecutive granules of one row -> coalesced).
__global__ __launch_bounds__(256, 4) void k_edge(const bf16_t* __restrict__ P, const bf16_t* __restrict__ Q,
                                                 const int* __restrict__ src, const bf16_t* __restrict__ Wp,
                                                 const float* __restrict__ mb1, const float* __restrict__ mb2,
                                                 bf16_t* __restrict__ SA) {
    __shared__ __align__(16) bf16_t act[16384];
    int tid = threadIdx.x;
    int g = blockIdx.y, b = blockIdx.x;
    int e0 = g * 120, n0 = g * 6;
    int nreal = (e0 + 120 <= EE) ? 120 : (EE - e0);   // 120 or 60
    int lane = tid & 63, w = tid >> 6;

    for (int ch = tid; ch < 2048; ch += 256) {
        int r = ch >> 4, p = ch & 15;
        uint4 o;
        if (r < nreal) {
            int e = e0 + r;
            int sn = src[e];
            int dn = n0 + r / 20;
            uint4 pv = *(const uint4*)(P + (((size_t)b * NN + sn) << 7) + (p << 3));
            uint4 qv = *(const uint4*)(Q + (((size_t)b * NN + dn) << 7) + (p << 3));
            o.x = addrelu2(pv.x, qv.x);
            o.y = addrelu2(pv.y, qv.y);
            o.z = addrelu2(pv.z, qv.z);
            o.w = addrelu2(pv.w, qv.w);
        } else {
            o.x = 0u; o.y = 0u; o.z = 0u; o.w = 0u;
        }
        *(uint4*)&act[pmjx(r, p)] = o;
    }
    __syncthreads();

    if (nreal == 120) {
        f32x16 acc[4];
        gemm_e<4>(acc, act, Wp + 2 * 16384, mb1, w, lane);   // act0 @ mW1 + mb1
        __syncthreads();
        wb_e<4>(act, acc, w, lane);                          // act1 = relu
        __syncthreads();
        gemm_e<4>(acc, act, Wp + 3 * 16384, mb2, w, lane);   // act1 @ mW2 + mb2
        __syncthreads();
        wb_e<4>(act, acc, w, lane);                          // act2 = relu
        __syncthreads();
    } else {                                                 // tail: rows 0..63 only
        f32x16 acc[2];
        gemm_e<2>(acc, act, Wp + 2 * 16384, mb1, w, lane);
        __syncthreads();
        wb_e<2>(act, acc, w, lane);
        __syncthreads();
        gemm_e<2>(acc, act, Wp + 3 * 16384, mb2, w, lane);
        __syncthreads();
        wb_e<2>(act, acc, w, lane);
        __syncthreads();
    }

    if (tid < 192) {
        int j = tid >> 5;
        int sub = tid & 31;
        int rr = sub >> 1;
        int half = sub & 1;
        int nodes = nreal / 20;
        if (j < nodes) {
            float s0 = 0.f, s1 = 0.f, s2 = 0.f, s3 = 0.f, s4 = 0.f, s5 = 0.f, s6 = 0.f, s7 = 0.f;
            #pragma unroll
            for (int i = 0; i < 10; i++) {
                int m = 20 * j + half * 10 + i;
                bf16x8 v = *(const bf16x8*)&act[pmjx(m, rr)];
                s0 += (float)v[0]; s1 += (float)v[1]; s2 += (float)v[2]; s3 += (float)v[3];
                s4 += (float)v[4]; s5 += (float)v[5]; s6 += (float)v[6]; s7 += (float)v[7];
            }
            s0 += __shfl_xor(s0, 1); s1 += __shfl_xor(s1, 1);
            s2 += __shfl_xor(s2, 1); s3 += __shfl_xor(s3, 1);
            s4 += __shfl_xor(s4, 1); s5 += __shfl_xor(s5, 1);
            s6 += __shfl_xor(s6, 1); s7 += __shfl_xor(s7, 1);
            if (half == 0) {
                uint4 o;
                o.x = pkbf(s0, s1); o.y = pkbf(s2, s3);
                o.z = pkbf(s4, s5); o.w = pkbf(s6, s7);
                *(uint4*)(SA + (((size_t)b * NN + n0 + j) << 7) + (rr << 3)) = o;
            }
        }
    }
}

// ---------------- node kernel: bf16 h/C2, M=32, 4 waves x N=32 ----------------
__global__ __launch_bounds__(256, 6) void k_node(bf16_t* __restrict__ hb, const bf16_t* __restrict__ SA,
                                                 const bf16_t* __restrict__ C2b, const bf16_t* __restrict__ Wp,
                                                 const float* __restrict__ nb1, const float* __restrict__ nb2,
                                                 const float* __restrict__ nb3, const float* __restrict__ ln_g,
                                                 const float* __restrict__ ln_b, const float* __restrict__ mb0,
                                                 bf16_t* __restrict__ Pd, bf16_t* __restrict__ Qd) {
    __shared__ __align__(16) bf16_t act[4096];   // 32 rows x 128
    __shared__ __align__(16) bf16_t sab[4096];   // staged SA
    __shared__ float st[256];                    // 32 rows x 4 waves x {s1,s2}
    int tid = threadIdx.x;
    size_t i0 = (size_t)blockIdx.x * 32;
    int lane = tid & 63, wid = tid >> 6;
    int lrow = lane & 15, q = lane >> 4;
    int colb = wid * 32;

    // stage h (raw bf16 copy) and SA in one pass
    for (int ch = tid; ch < 1024; ch += 256) {
        if (ch < 512) {
            int r = ch >> 4, p = ch & 15;
            *(uint4*)&act[swz(r, p << 3)] = *(const uint4*)(hb + (i0 + r) * 128 + (p << 3));
        } else {
            int r = (ch - 512) >> 4, p = ch & 15;
            *(uint4*)&sab[swz(r, p << 3)] = *(const uint4*)(SA + (i0 + r) * 128 + (p << 3));
        }
    }
    __syncthreads();
    f32x4 acc[2][2];
    gemm32s(acc, act, Wp + 4 * 16384, wid, lane, lrow, q, true);     // h @ nW0a
    gemm32s(acc, sab, Wp + 5 * 16384, wid, lane, lrow, q, false);    // + SA @ Ft
    __syncthreads();
    // u0 = relu(acc + C2)
    #pragma unroll
    for (int nt = 0; nt < 2; nt++) {
        int nb = colb + nt * 16 + q * 4;
        #pragma unroll
        for (int mt = 0; mt < 2; mt++) {
            int m = mt * 16 + lrow;
            uint2 cv = *(const uint2*)(C2b + (i0 + m) * 128 + nb);
            uint2 u;
            u.x = pkbf_t(fmaxf(acc[nt][mt][0] + bflo(cv.x), 0.f), fmaxf(acc[nt][mt][1] + bfhi(cv.x), 0.f));
            u.y = pkbf_t(fmaxf(acc[nt][mt][2] + bflo(cv.y), 0.f), fmaxf(acc[nt][mt][3] + bfhi(cv.y), 0.f));
            *(uint2*)&act[swz(m, nb)] = u;
        }
    }
    __syncthreads();
    gemm32s(acc, act, Wp + 6 * 16384, wid, lane, lrow, q, true);     // nW1
    __syncthreads();
    wb32(act, acc, nb1, colb, lrow, q);
    __syncthreads();
    gemm32s(acc, act, Wp + 7 * 16384, wid, lane, lrow, q, true);     // nW2
    __syncthreads();
    wb32(act, acc, nb2, colb, lrow, q);
    __syncthreads();
    gemm32s(acc, act, Wp + 8 * 16384, wid, lane, lrow, q, true);     // nW3

    // residual v = acc + nb3 + h(bf16), LN stats
    float s1[2] = {0.f, 0.f}, s2[2] = {0.f, 0.f};
    #pragma unroll
    for (int nt = 0; nt < 2; nt++) {
        int nb = colb + nt * 16 + q * 4;
        float4 b4 = *(const float4*)&nb3[nb];
        #pragma unroll
        for (int mt = 0; mt < 2; mt++) {
            int m = mt * 16 + lrow;
            uint2 hv = *(const uint2*)(hb + (i0 + m) * 128 + nb);
            float v0 = acc[nt][mt][0] + b4.x + bflo(hv.x);
            float v1 = acc[nt][mt][1] + b4.y + bfhi(hv.x);
            float v2 = acc[nt][mt][2] + b4.z + bflo(hv.y);
            float v3 = acc[nt][mt][3] + b4.w + bfhi(hv.y);
            acc[nt][mt][0] = v0; acc[nt][mt][1] = v1;
            acc[nt][mt][2] = v2; acc[nt][mt][3] = v3;
            s1[mt] += v0 + v1 + v2 + v3;
            s2[mt] += v0 * v0 + v1 * v1 + v2 * v2 + v3 * v3;
        }
    }
    #pragma unroll
    for (int mt = 0; mt < 2; mt++) {
        float a = s1[mt], c = s2[mt];
        a += __shfl_xor(a, 16); c += __shfl_xor(c, 16);
        a += __shfl_xor(a, 32); c += __shfl_xor(c, 32);
        s1[mt] = a; s2[mt] = c;
    }
    if (q == 0) {
        #pragma unroll
        for (int mt = 0; mt < 2; mt++) {
            st[(mt * 16 + lrow) * 8 + wid * 2 + 0] = s1[mt];
            st[(mt * 16 + lrow) * 8 + wid * 2 + 1] = s2[mt];
        }
    }
    __syncthreads();
    float mu[2], rs[2];
    #pragma unroll
    for (int mt = 0; mt < 2; mt++) {
        int m = mt * 16 + lrow;
        float a = st[m * 8 + 0] + st[m * 8 + 2] + st[m * 8 + 4] + st[m * 8 + 6];
        float c = st[m * 8 + 1] + st[m * 8 + 3] + st[m * 8 + 5] + st[m * 8 + 7];
        a *= (1.f / 128.f); c *= (1.f / 128.f);
        mu[mt] = a;
        rs[mt] = rsqrtf(c - a * a + 1e-5f);
    }
    // LN apply -> hb (bf16 global) and act (same packed dwords)
    #pragma unroll
    for (int nt = 0; nt < 2; nt++) {
        int nb = colb + nt * 16 + q * 4;
        float4 g4 = *(const float4*)&ln_g[nb];
        float4 bb4 = *(const float4*)&ln_b[nb];
        #pragma unroll
        for (int mt = 0; mt < 2; mt++) {
            int m = mt * 16 + lrow;
            float o0 = (acc[nt][mt][0] - mu[mt]) * rs[mt] * g4.x + bb4.x;
            float o1 = (acc[nt][mt][1] - mu[mt]) * rs[mt] * g4.y + bb4.y;
            float o2 = (acc[nt][mt][2] - mu[mt]) * rs[mt] * g4.z + bb4.z;
            float o3 = (acc[nt][mt][3] - mu[mt]) * rs[mt] * g4.w + bb4.w;
            uint2 u;
            u.x = pkbf(o0, o1); u.y = pkbf(o2, o3);
            *(uint2*)(hb + (i0 + m) * 128 + nb) = u;
            *(uint2*)&act[swz(m, nb)] = u;
        }
    }
    __syncthreads();
    gemm32s(acc, act, Wp + 0 * 16384, wid, lane, lrow, q, true);     // mW0a -> P
    #pragma unroll
    for (int nt = 0; nt < 2; nt++) {
        int nb = colb + nt * 16 + q * 4;
        #pragma unroll
        for (int mt = 0; mt < 2; mt++) {
            int m = mt * 16 + lrow;
            uint2 u;
            u.x = pkbf(acc[nt][mt][0], acc[nt][mt][1]);
            u.y = pkbf(acc[nt][mt][2], acc[nt][mt][3]);
            *(uint2*)(Pd + (i0 + m) * 128 + nb) = u;
        }
    }
    gemm32s(acc, act, Wp + 1 * 16384, wid, lane, lrow, q, true);     // mW0b -> Q' (+mb0)
    #pragma unroll
    for (int nt = 0; nt < 2; nt++) {
        int nb = colb + nt * 16 + q * 4;
        float4 m4 = *(const float4*)&mb0[nb];
        #pragma unroll
        for (int mt = 0; mt < 2; mt++) {
            int m = mt * 16 + lrow;
            uint2 u;
            u.x = pkbf(acc[nt][mt][0] + m4.x, acc[nt][mt][1] + m4.y);
            u.y = pkbf(acc[nt][mt][2] + m4.z, acc[nt][mt][3] + m4.w);
            *(uint2*)(Qd + (i0 + m) * 128 + nb) = u;
        }
    }
}

__global__ __launch_bounds__(256) void k_out(const bf16_t* __restrict__ hb, const float* __restrict__ W_out,
                                             const float* __restrict__ b_out, float* __restrict__ out) {
    int idx = blockIdx.x * 256 + threadIdx.x;   // < BN*9
    int row = idx / 9, o = idx - row * 9;
    const bf16_t* hr = hb + (size_t)row * 128;
    float s = b_out[o];
    #pragma unroll 4
    for (int k8 = 0; k8 < 16; k8++) {
        bf16x8 v = *(const bf16x8*)(hr + k8 * 8);
        int kb = k8 * 8;
        #pragma unroll
        for (int j = 0; j < 8; j++) s += (float)v[j] * W_out[(kb + j) * 9 + o];
    }
    out[idx] = s;
}

extern "C" void kernel_launch(void* const* d_in, const int* in_sizes, int n_in,
                              void* d_out, int out_size, void* d_ws, size_t ws_size,
                              hipStream_t stream) {
    const float* x    = (const float*)d_in[0];
    const int*   src  = (const int*)d_in[1];
    const float* W_in = (const float*)d_in[3];
    const float* b_in = (const float*)d_in[4];
    const float* pos  = (const float*)d_in[5];
    const float* mW0  = (const float*)d_in[6];
    const float* mb0  = (const float*)d_in[7];
    const float* mW1  = (const float*)d_in[8];
    const float* mb1  = (const float*)d_in[9];
    const float* mW2  = (const float*)d_in[10];
    const float* mb2  = (const float*)d_in[11];
    const float* mW3  = (const float*)d_in[12];
    const float* mb3  = (const float*)d_in[13];
    const float* nW0  = (const float*)d_in[14];
    const float* nb0  = (const float*)d_in[15];
    const float* nW1  = (const float*)d_in[16];
    const float* nb1  = (const float*)d_in[17];
    const float* nW2  = (const float*)d_in[18];
    const float* nb2  = (const float*)d_in[19];
    const float* nW3  = (const float*)d_in[20];
    const float* nb3  = (const float*)d_in[21];
    const float* ln_g = (const float*)d_in[22];
    const float* ln_b = (const float*)d_in[23];
    const float* W_out= (const float*)d_in[24];
    const float* b_out= (const float*)d_in[25];

    char* ws = (char*)d_ws;
    bf16_t* hb  = (bf16_t*)ws;                      // 10,616,832 B (bf16 h; also x_embed)
    bf16_t* C2b = (bf16_t*)(ws + 10616832);         // 10,616,832 B
    bf16_t* SA  = (bf16_t*)(ws + 21233664);         // 10,616,832 B
    bf16_t* P   = (bf16_t*)(ws + 31850496);         // 10,616,832 B
    bf16_t* Q   = (bf16_t*)(ws + 42467328);         // 10,616,832 B (holds Q' = Q+mb0)
    bf16_t* Wp  = (bf16_t*)(ws + 53084160);         // 10 * 32,768 B (packed bf16)
    float*  bfix= (float*)(ws + 53411840);          // 512 B

    k_embed<<<20736, 256, 0, stream>>>(x, W_in, b_in, pos, hb);

    // packed slots: 0=mW0a 1=mW0b 2=mW1(32x32) 3=mW2(32x32) 4=nW0a(h) 5=Ft 6=nW1 7=nW2 8=nW3 9=nW0b(x)
    PackArgs pa;
    pa.s[0] = mW0;  pa.s[1] = mW0 + 16384; pa.s[2] = mW1; pa.s[3] = mW2;
    pa.s[4] = nW0;  pa.s[5] = nW1;  pa.s[6] = nW2;  pa.s[7] = nW3;  pa.s[8] = nW0 + 16384;
    k_pack_all<<<576, 256, 0, stream>>>(pa, Wp);
    k_fuse<<<64, 256, 0, stream>>>(mW3, nW0, Wp + 5 * 16384);
    k_bias<<<1, 128, 0, stream>>>(nb0, mb3, nW0, bfix);

    k_simple3<<<972, 256, 0, stream>>>(hb, Wp, bfix, mb0, C2b, P, Q);   // C2, P0, Q'0

    for (int s = 0; s < 16; s++) {
        k_edge<<<dim3(512, 14), 256, 0, stream>>>(P, Q, src, Wp, mb1, mb2, SA);
        k_node<<<1296, 256, 0, stream>>>(hb, SA, C2b, Wp, nb1, nb2, nb3, ln_g, ln_b, mb0, P, Q);
    }
    k_out<<<1458, 256, 0, stream>>>(hb, W_out, b_out, (float*)d_out);
}

// Round 10
// 2105.989 us; speedup vs baseline: 1.0004x; 1.0004x over previous
//
#include <hip/hip_runtime.h>
#include <hip/hip_bf16.h>

typedef __bf16 bf16_t;
typedef bf16_t bf16x8 __attribute__((ext_vector_type(8)));
typedef bf16_t bf16x4 __attribute__((ext_vector_type(4)));
typedef float  f32x4  __attribute__((ext_vector_type(4)));
typedef float  f32x16 __attribute__((ext_vector_type(16)));

#define NN   81
#define BB   512
#define BN   41472          // 512*81
#define EE   1620

// 4-bit XOR swizzle on the 16B granule index.
__device__ __forceinline__ int swz(int r, int k) {
    return (r << 7) + ((((k >> 3) ^ (r & 15)) << 3) | (k & 7));
}

// 16x16x32 packed-weight offset (prep + node kernels)
__device__ __forceinline__ int wpack(int n, int k) {
    return ((n >> 6) << 13) + (((((k >> 5) << 2) + ((n >> 4) & 3))) << 9)
         + (((((k >> 3) & 3) << 4) + (n & 15)) << 3) + (k & 7);
}

// 32x32x16 packed-weight offset (edge kernel)
__device__ __forceinline__ int wpack32(int n, int k) {
    return ((((k >> 4) << 2) | (n >> 5)) << 9)
         + (((((k >> 3) & 1) << 5) | (n & 31)) << 3) + (k & 7);
}

// pack two f32 -> bf16x2, round-half-up: 2 adds + 1 v_perm
__device__ __forceinline__ unsigned pkbf(float lo, float hi) {
    unsigned a = __float_as_uint(lo) + 0x8000u;
    unsigned b = __float_as_uint(hi) + 0x8000u;
    return __builtin_amdgcn_perm(b, a, 0x07060302);
}

// truncating pack (1 v_perm) — intra-step activations only
__device__ __forceinline__ unsigned pkbf_t(float lo, float hi) {
    return __builtin_amdgcn_perm(__float_as_uint(hi), __float_as_uint(lo), 0x07060302);
}

__device__ __forceinline__ float bflo(unsigned d) { return __uint_as_float(d << 16); }
__device__ __forceinline__ float bfhi(unsigned d) { return __uint_as_float(d & 0xffff0000u); }

// relu(p+q) on packed bf16x2, all-f32 path (native v_max_f32)
__device__ __forceinline__ unsigned addrelu2(unsigned pd, unsigned qd) {
    float lo = fmaxf(bflo(pd) + bflo(qd), 0.f);
    float hi = fmaxf(bfhi(pd) + bfhi(qd), 0.f);
    return pkbf(lo, hi);
}

// ---------------- 16x16x32 GEMM (prep + node) ----------------
__device__ __forceinline__ void gemm128s(f32x4 (&acc)[4][4], const bf16_t* act,
                                         const bf16_t* __restrict__ Wp,
                                         int wm, int wn, int lane, int lrow, int q) {
    f32x4 z = {0.f, 0.f, 0.f, 0.f};
    #pragma unroll
    for (int i = 0; i < 4; i++)
        #pragma unroll
        for (int j = 0; j < 4; j++) acc[i][j] = z;
    const bf16_t* wbase = Wp + (wn << 13) + (lane << 3);
    #pragma unroll
    for (int k0 = 0; k0 < 128; k0 += 32) {
        bf16x8 af[4], wf[4];
        #pragma unroll
        for (int mt = 0; mt < 4; mt++)
            af[mt] = *(const bf16x8*)&act[swz(wm * 64 + mt * 16 + lrow, k0 + q * 8)];
        #pragma unroll
        for (int nt = 0; nt < 4; nt++)
            wf[nt] = *(const bf16x8*)(wbase + ((((k0 >> 5) << 2) + nt) << 9));
        #pragma unroll
        for (int nt = 0; nt < 4; nt++)
            #pragma unroll
            for (int mt = 0; mt < 4; mt++)
                acc[nt][mt] = __builtin_amdgcn_mfma_f32_16x16x32_bf16(wf[nt], af[mt], acc[nt][mt], 0, 0, 0);
    }
}

// ---------------- edge-kernel GEMM: wave tile M=64 rows x N=32 cols ----------------
// 60-edge (64-row) tiles: LDS 16KB + acc 32 f32 -> 5 blocks/CU (was 4 at
// 128-row/32KB). Rounds 7-9 showed the kernel is latency/barrier-bound
// (VALU and conflict cuts didn't move dur); this buys +25% resident blocks
// at the cost of 2x weight L2 traffic (the round-3/5 counter-lever).
__device__ __forceinline__ void gemm_e2(f32x16 (&acc)[2], const bf16_t* act,
                                        const bf16_t* __restrict__ W,
                                        const float* __restrict__ bias,
                                        int wid, int lane) {
    int lm = lane & 31, h = lane >> 5;
    #pragma unroll
    for (int gg = 0; gg < 4; gg++) {
        float4 b4 = *(const float4*)&bias[wid * 32 + 8 * gg + 4 * h];
        #pragma unroll
        for (int mt = 0; mt < 2; mt++) {
            acc[mt][4 * gg + 0] = b4.x; acc[mt][4 * gg + 1] = b4.y;
            acc[mt][4 * gg + 2] = b4.z; acc[mt][4 * gg + 3] = b4.w;
        }
    }
    const bf16_t* wl = W + (lane << 3);
    #pragma unroll
    for (int kk = 0; kk < 8; kk++) {
        bf16x8 wf = *(const bf16x8*)(wl + (((kk << 2) + wid) << 9));
        #pragma unroll
        for (int mt = 0; mt < 2; mt++) {
            bf16x8 af = *(const bf16x8*)&act[swz(mt * 32 + lm, kk * 16 + h * 8)];
            acc[mt] = __builtin_amdgcn_mfma_f32_32x32x16_bf16(wf, af, acc[mt], 0, 0, 0);
        }
    }
}

__device__ __forceinline__ void wb_e2(bf16_t* act, f32x16 (&acc)[2], int wid, int lane) {
    int lm = lane & 31, h = lane >> 5;
    #pragma unroll
    for (int mt = 0; mt < 2; mt++)
        #pragma unroll
        for (int gg = 0; gg < 4; gg++) {
            int nb = wid * 32 + 8 * gg + 4 * h;
            int m = mt * 32 + lm;
            uint2 u;
            u.x = pkbf_t(fmaxf(acc[mt][4 * gg + 0], 0.f), fmaxf(acc[mt][4 * gg + 1], 0.f));
            u.y = pkbf_t(fmaxf(acc[mt][4 * gg + 2], 0.f), fmaxf(acc[mt][4 * gg + 3], 0.f));
            *(uint2*)&act[swz(m, nb)] = u;
        }
}

// ---------------- node-kernel GEMM: wave tile 32(M) x 32(N) ----------------
__device__ __forceinline__ void gemm32s(f32x4 (&acc)[2][2], const bf16_t* act,
                                        const bf16_t* __restrict__ Wp,
                                        int wid, int lane, int lrow, int q, bool zero) {
    if (zero) {
        f32x4 z = {0.f, 0.f, 0.f, 0.f};
        acc[0][0] = z; acc[0][1] = z; acc[1][0] = z; acc[1][1] = z;
    }
    int wn = wid >> 1, ntb = (wid & 1) << 1;
    const bf16_t* wbase = Wp + (wn << 13) + (lane << 3);
    #pragma unroll
    for (int k0 = 0; k0 < 128; k0 += 32) {
        bf16x8 af[2], wf[2];
        af[0] = *(const bf16x8*)&act[swz(lrow, k0 + q * 8)];
        af[1] = *(const bf16x8*)&act[swz(16 + lrow, k0 + q * 8)];
        wf[0] = *(const bf16x8*)(wbase + ((((k0 >> 5) << 2) + ntb) << 9));
        wf[1] = *(const bf16x8*)(wbase + ((((k0 >> 5) << 2) + ntb + 1) << 9));
        #pragma unroll
        for (int nt = 0; nt < 2; nt++)
            #pragma unroll
            for (int mt = 0; mt < 2; mt++)
                acc[nt][mt] = __builtin_amdgcn_mfma_f32_16x16x32_bf16(wf[nt], af[mt], acc[nt][mt], 0, 0, 0);
    }
}

__device__ __forceinline__ void wb32(bf16_t* act, f32x4 (&acc)[2][2], const float* __restrict__ bias,
                                     int colb, int lrow, int q) {
    #pragma unroll
    for (int nt = 0; nt < 2; nt++) {
        int nb = colb + nt * 16 + q * 4;
        float4 b4 = *(const float4*)&bias[nb];
        #pragma unroll
        for (int mt = 0; mt < 2; mt++) {
            int m = mt * 16 + lrow;
            uint2 u;
            u.x = pkbf_t(fmaxf(acc[nt][mt][0] + b4.x, 0.f), fmaxf(acc[nt][mt][1] + b4.y, 0.f));
            u.y = pkbf_t(fmaxf(acc[nt][mt][2] + b4.z, 0.f), fmaxf(acc[nt][mt][3] + b4.w, 0.f));
            *(uint2*)&act[swz(m, nb)] = u;
        }
    }
}

// ---------------- prep kernels ----------------

__global__ __launch_bounds__(256) void k_embed(const float* __restrict__ x, const float* __restrict__ W_in,
                                               const float* __restrict__ b_in, const float* __restrict__ pos,
                                               bf16_t* __restrict__ hb) {
    int idx = blockIdx.x * 256 + threadIdx.x;   // < BN*128
    int row = idx >> 7, col = idx & 127;
    int n = row % NN;
    const float* xr = x + (size_t)row * 10;
    float s = b_in[col] + pos[n * 128 + col];
    #pragma unroll
    for (int k = 0; k < 10; k++) s += xr[k] * W_in[k * 128 + col];
    hb[idx] = (bf16_t)s;
}

struct PackArgs { const float* s[9]; };

__global__ __launch_bounds__(256) void k_pack_all(PackArgs pa, bf16_t* __restrict__ dst) {
    const int slot[9] = {0, 1, 2, 3, 4, 6, 7, 8, 9};
    int idx = blockIdx.x * 256 + threadIdx.x;   // < 9*16384
    int w = idx >> 14, r = idx & 16383;
    int n = r >> 7, k = r & 127;
    int po = (w == 2 || w == 3) ? wpack32(n, k) : wpack(n, k);   // edge weights use 32x32 layout
    dst[slot[w] * 16384 + po] = (bf16_t)pa.s[w][k * 128 + n];
}

__global__ __launch_bounds__(256) void k_fuse(const float* __restrict__ mW3, const float* __restrict__ nW0,
                                              bf16_t* __restrict__ Ft) {
    int idx = blockIdx.x * 256 + threadIdx.x;   // < 16384
    int n = idx >> 7, k = idx & 127;
    float s = 0.f;
    for (int j = 0; j < 128; j++) s += mW3[k * 128 + j] * nW0[(256 + j) * 128 + n];
    Ft[wpack(n, k)] = (bf16_t)s;
}

__global__ __launch_bounds__(128) void k_bias(const float* __restrict__ nb0, const float* __restrict__ mb3,
                                              const float* __restrict__ nW0, float* __restrict__ bfix) {
    int n = threadIdx.x;
    float s = 0.f;
    for (int j = 0; j < 128; j++) s += mb3[j] * nW0[(256 + j) * 128 + n];
    bfix[n] = nb0[n] + 20.f * s;
}

// one launch does C2 (bf16, bias=bfix), P (bf16), Q' (bf16, bias=mb0); input hb is bf16
__global__ __launch_bounds__(256, 2) void k_simple3(const bf16_t* __restrict__ in,
                                                    const bf16_t* __restrict__ Wp,
                                                    const float* __restrict__ bfix,
                                                    const float* __restrict__ mb0,
                                                    bf16_t* __restrict__ C2b,
                                                    bf16_t* __restrict__ Pd,
                                                    bf16_t* __restrict__ Qd) {
    __shared__ __align__(16) bf16_t act[16384];
    int tid = threadIdx.x;
    int sel = blockIdx.x / 324, blk = blockIdx.x - sel * 324;
    size_t i0 = (size_t)blk * 128;
    int lane = tid & 63, wid = tid >> 6;
    int wm = wid >> 1, wn = wid & 1, lrow = lane & 15, q = lane >> 4;

    for (int ch = tid; ch < 2048; ch += 256) {      // raw bf16 stage
        int r = ch >> 4, p = ch & 15;
        *(uint4*)&act[swz(r, p << 3)] = *(const uint4*)(in + (i0 + r) * 128 + (p << 3));
    }
    __syncthreads();
    const bf16_t* W = Wp + (sel == 0 ? 9 * 16384 : (sel == 1 ? 0 : 16384));
    f32x4 acc[4][4];
    gemm128s(acc, act, W, wm, wn, lane, lrow, q);
    bf16_t* dst = (sel == 0) ? C2b : ((sel == 1) ? Pd : Qd);
    #pragma unroll
    for (int nt = 0; nt < 4; nt++) {
        int nb = wn * 64 + nt * 16 + q * 4;
        float4 b4 = (sel == 0) ? *(const float4*)&bfix[nb]
                  : (sel == 2) ? *(const float4*)&mb0[nb]
                               : make_float4(0.f, 0.f, 0.f, 0.f);
        #pragma unroll
        for (int mt = 0; mt < 4; mt++) {
            int m = wm * 64 + mt * 16 + lrow;
            uint2 u;
            u.x = pkbf(acc[nt][mt][0] + b4.x, acc[nt][mt][1] + b4.y);
            u.y = pkbf(acc[nt][mt][2] + b4.z, acc[nt][mt][3] + b4.w);
            *(uint2*)(dst + (i0 + m) * 128 + nb) = u;
        }
    }
}

// ---------------- edge kernel: 32x32x16 MFMA, 60-edge tiles, 5 blocks/CU ----------------
// Grid (b=512, g=27): 1620 = 27*60 -> uniform groups of 3 nodes, zero tail
// divergence. Consecutive blockIdx.x = batch keeps per-XCD P/Q working set
// L2-resident (round-6 win: FETCH 42.7MB -> 10.7MB). Staging lane order is
// round-6's (16 consecutive lanes read 16 consecutive granules of one row ->
// coalesced; round-7 showed breaking this regresses).
__global__ __launch_bounds__(256, 5) void k_edge(const bf16_t* __restrict__ P, const bf16_t* __restrict__ Q,
                                                 const int* __restrict__ src, const bf16_t* __restrict__ Wp,
                                                 const float* __restrict__ mb1, const float* __restrict__ mb2,
                                                 bf16_t* __restrict__ SA) {
    __shared__ __align__(16) bf16_t act[8192];      // 64 rows x 128, 16KB
    int tid = threadIdx.x;
    int g = blockIdx.y, b = blockIdx.x;
    int e0 = g * 60, n0 = g * 3;
    int lane = tid & 63, w = tid >> 6;

    for (int ch = tid; ch < 1024; ch += 256) {
        int r = ch >> 4, p = ch & 15;
        uint4 o;
        if (r < 60) {
            int e = e0 + r;
            int sn = src[e];
            int dn = n0 + r / 20;
            uint4 pv = *(const uint4*)(P + (((size_t)b * NN + sn) << 7) + (p << 3));
            uint4 qv = *(const uint4*)(Q + (((size_t)b * NN + dn) << 7) + (p << 3));
            o.x = addrelu2(pv.x, qv.x);
            o.y = addrelu2(pv.y, qv.y);
            o.z = addrelu2(pv.z, qv.z);
            o.w = addrelu2(pv.w, qv.w);
        } else {
            o.x = 0u; o.y = 0u; o.z = 0u; o.w = 0u;
        }
        *(uint4*)&act[swz(r, p << 3)] = o;
    }
    __syncthreads();

    f32x16 acc[2];
    gemm_e2(acc, act, Wp + 2 * 16384, mb1, w, lane);     // act0 @ mW1 + mb1
    __syncthreads();
    wb_e2(act, acc, w, lane);                            // act1 = relu
    __syncthreads();
    gemm_e2(acc, act, Wp + 3 * 16384, mb2, w, lane);     // act1 @ mW2 + mb2
    __syncthreads();
    wb_e2(act, acc, w, lane);                            // act2 = relu
    __syncthreads();

    if (tid < 96) {                                      // 3 nodes x 32 threads
        int j = tid >> 5;
        int sub = tid & 31;
        int rr = sub >> 1;
        int half = sub & 1;
        float s0 = 0.f, s1 = 0.f, s2 = 0.f, s3 = 0.f, s4 = 0.f, s5 = 0.f, s6 = 0.f, s7 = 0.f;
        #pragma unroll
        for (int i = 0; i < 10; i++) {
            int m = 20 * j + half * 10 + i;
            bf16x8 v = *(const bf16x8*)&act[swz(m, rr << 3)];
            s0 += (float)v[0]; s1 += (float)v[1]; s2 += (float)v[2]; s3 += (float)v[3];
            s4 += (float)v[4]; s5 += (float)v[5]; s6 += (float)v[6]; s7 += (float)v[7];
        }
        s0 += __shfl_xor(s0, 1); s1 += __shfl_xor(s1, 1);
        s2 += __shfl_xor(s2, 1); s3 += __shfl_xor(s3, 1);
        s4 += __shfl_xor(s4, 1); s5 += __shfl_xor(s5, 1);
        s6 += __shfl_xor(s6, 1); s7 += __shfl_xor(s7, 1);
        if (half == 0) {
            uint4 o;
            o.x = pkbf(s0, s1); o.y = pkbf(s2, s3);
            o.z = pkbf(s4, s5); o.w = pkbf(s6, s7);
            *(uint4*)(SA + (((size_t)b * NN + n0 + j) << 7) + (rr << 3)) = o;
        }
    }
}

// ---------------- node kernel: bf16 h/C2, M=32, 4 waves x N=32 ----------------
__global__ __launch_bounds__(256, 6) void k_node(bf16_t* __restrict__ hb, const bf16_t* __restrict__ SA,
                                                 const bf16_t* __restrict__ C2b, const bf16_t* __restrict__ Wp,
                                                 const float* __restrict__ nb1, const float* __restrict__ nb2,
                                                 const float* __restrict__ nb3, const float* __restrict__ ln_g,
                                                 const float* __restrict__ ln_b, const float* __restrict__ mb0,
                                                 bf16_t* __restrict__ Pd, bf16_t* __restrict__ Qd) {
    __shared__ __align__(16) bf16_t act[4096];   // 32 rows x 128
    __shared__ __align__(16) bf16_t sab[4096];   // staged SA
    __shared__ float st[256];                    // 32 rows x 4 waves x {s1,s2}
    int tid = threadIdx.x;
    size_t i0 = (size_t)blockIdx.x * 32;
    int lane = tid & 63, wid = tid >> 6;
    int lrow = lane & 15, q = lane >> 4;
    int colb = wid * 32;

    // stage h (raw bf16 copy) and SA in one pass
    for (int ch = tid; ch < 1024; ch += 256) {
        if (ch < 512) {
            int r = ch >> 4, p = ch & 15;
            *(uint4*)&act[swz(r, p << 3)] = *(const uint4*)(hb + (i0 + r) * 128 + (p << 3));
        } else {
            int r = (ch - 512) >> 4, p = ch & 15;
            *(uint4*)&sab[swz(r, p << 3)] = *(const uint4*)(SA + (i0 + r) * 128 + (p << 3));
        }
    }
    __syncthreads();
    f32x4 acc[2][2];
    gemm32s(acc, act, Wp + 4 * 16384, wid, lane, lrow, q, true);     // h @ nW0a
    gemm32s(acc, sab, Wp + 5 * 16384, wid, lane, lrow, q, false);    // + SA @ Ft
    __syncthreads();
    // u0 = relu(acc + C2)
    #pragma unroll
    for (int nt = 0; nt < 2; nt++) {
        int nb = colb + nt * 16 + q * 4;
        #pragma unroll
        for (int mt = 0; mt < 2; mt++) {
            int m = mt * 16 + lrow;
            uint2 cv = *(const uint2*)(C2b + (i0 + m) * 128 + nb);
            uint2 u;
            u.x = pkbf_t(fmaxf(acc[nt][mt][0] + bflo(cv.x), 0.f), fmaxf(acc[nt][mt][1] + bfhi(cv.x), 0.f));
            u.y = pkbf_t(fmaxf(acc[nt][mt][2] + bflo(cv.y), 0.f), fmaxf(acc[nt][mt][3] + bfhi(cv.y), 0.f));
            *(uint2*)&act[swz(m, nb)] = u;
        }
    }
    __syncthreads();
    gemm32s(acc, act, Wp + 6 * 16384, wid, lane, lrow, q, true);     // nW1
    __syncthreads();
    wb32(act, acc, nb1, colb, lrow, q);
    __syncthreads();
    gemm32s(acc, act, Wp + 7 * 16384, wid, lane, lrow, q, true);     // nW2
    __syncthreads();
    wb32(act, acc, nb2, colb, lrow, q);
    __syncthreads();
    gemm32s(acc, act, Wp + 8 * 16384, wid, lane, lrow, q, true);     // nW3

    // residual v = acc + nb3 + h(bf16), LN stats
    float s1[2] = {0.f, 0.f}, s2[2] = {0.f, 0.f};
    #pragma unroll
    for (int nt = 0; nt < 2; nt++) {
        int nb = colb + nt * 16 + q * 4;
        float4 b4 = *(const float4*)&nb3[nb];
        #pragma unroll
        for (int mt = 0; mt < 2; mt++) {
            int m = mt * 16 + lrow;
            uint2 hv = *(const uint2*)(hb + (i0 + m) * 128 + nb);
            float v0 = acc[nt][mt][0] + b4.x + bflo(hv.x);
            float v1 = acc[nt][mt][1] + b4.y + bfhi(hv.x);
            float v2 = acc[nt][mt][2] + b4.z + bflo(hv.y);
            float v3 = acc[nt][mt][3] + b4.w + bfhi(hv.y);
            acc[nt][mt][0] = v0; acc[nt][mt][1] = v1;
            acc[nt][mt][2] = v2; acc[nt][mt][3] = v3;
            s1[mt] += v0 + v1 + v2 + v3;
            s2[mt] += v0 * v0 + v1 * v1 + v2 * v2 + v3 * v3;
        }
    }
    #pragma unroll
    for (int mt = 0; mt < 2; mt++) {
        float a = s1[mt], c = s2[mt];
        a += __shfl_xor(a, 16); c += __shfl_xor(c, 16);
        a += __shfl_xor(a, 32); c += __shfl_xor(c, 32);
        s1[mt] = a; s2[mt] = c;
    }
    if (q == 0) {
        #pragma unroll
        for (int mt = 0; mt < 2; mt++) {
            st[(mt * 16 + lrow) * 8 + wid * 2 + 0] = s1[mt];
            st[(mt * 16 + lrow) * 8 + wid * 2 + 1] = s2[mt];
        }
    }
    __syncthreads();
    float mu[2], rs[2];
    #pragma unroll
    for (int mt = 0; mt < 2; mt++) {
        int m = mt * 16 + lrow;
        float a = st[m * 8 + 0] + st[m * 8 + 2] + st[m * 8 + 4] + st[m * 8 + 6];
        float c = st[m * 8 + 1] + st[m * 8 + 3] + st[m * 8 + 5] + st[m * 8 + 7];
        a *= (1.f / 128.f); c *= (1.f / 128.f);
        mu[mt] = a;
        rs[mt] = rsqrtf(c - a * a + 1e-5f);
    }
    // LN apply -> hb (bf16 global) and act (same packed dwords)
    #pragma unroll
    for (int nt = 0; nt < 2; nt++) {
        int nb = colb + nt * 16 + q * 4;
        float4 g4 = *(const float4*)&ln_g[nb];
        float4 bb4 = *(const float4*)&ln_b[nb];
        #pragma unroll
        for (int mt = 0; mt < 2; mt++) {
            int m = mt * 16 + lrow;
            float o0 = (acc[nt][mt][0] - mu[mt]) * rs[mt] * g4.x + bb4.x;
            float o1 = (acc[nt][mt][1] - mu[mt]) * rs[mt] * g4.y + bb4.y;
            float o2 = (acc[nt][mt][2] - mu[mt]) * rs[mt] * g4.z + bb4.z;
            float o3 = (acc[nt][mt][3] - mu[mt]) * rs[mt] * g4.w + bb4.w;
            uint2 u;
            u.x = pkbf(o0, o1); u.y = pkbf(o2, o3);
            *(uint2*)(hb + (i0 + m) * 128 + nb) = u;
            *(uint2*)&act[swz(m, nb)] = u;
        }
    }
    __syncthreads();
    gemm32s(acc, act, Wp + 0 * 16384, wid, lane, lrow, q, true);     // mW0a -> P
    #pragma unroll
    for (int nt = 0; nt < 2; nt++) {
        int nb = colb + nt * 16 + q * 4;
        #pragma unroll
        for (int mt = 0; mt < 2; mt++) {
            int m = mt * 16 + lrow;
            uint2 u;
            u.x = pkbf(acc[nt][mt][0], acc[nt][mt][1]);
            u.y = pkbf(acc[nt][mt][2], acc[nt][mt][3]);
            *(uint2*)(Pd + (i0 + m) * 128 + nb) = u;
        }
    }
    gemm32s(acc, act, Wp + 1 * 16384, wid, lane, lrow, q, true);     // mW0b -> Q' (+mb0)
    #pragma unroll
    for (int nt = 0; nt < 2; nt++) {
        int nb = colb + nt * 16 + q * 4;
        float4 m4 = *(const float4*)&mb0[nb];
        #pragma unroll
        for (int mt = 0; mt < 2; mt++) {
            int m = mt * 16 + lrow;
            uint2 u;
            u.x = pkbf(acc[nt][mt][0] + m4.x, acc[nt][mt][1] + m4.y);
            u.y = pkbf(acc[nt][mt][2] + m4.z, acc[nt][mt][3] + m4.w);
            *(uint2*)(Qd + (i0 + m) * 128 + nb) = u;
        }
    }
}

__global__ __launch_bounds__(256) void k_out(const bf16_t* __restrict__ hb, const float* __restrict__ W_out,
                                             const float* __restrict__ b_out, float* __restrict__ out) {
    int idx = blockIdx.x * 256 + threadIdx.x;   // < BN*9
    int row = idx / 9, o = idx - row * 9;
    const bf16_t* hr = hb + (size_t)row * 128;
    float s = b_out[o];
    #pragma unroll 4
    for (int k8 = 0; k8 < 16; k8++) {
        bf16x8 v = *(const bf16x8*)(hr + k8 * 8);
        int kb = k8 * 8;
        #pragma unroll
        for (int j = 0; j < 8; j++) s += (float)v[j] * W_out[(kb + j) * 9 + o];
    }
    out[idx] = s;
}

extern "C" void kernel_launch(void* const* d_in, const int* in_sizes, int n_in,
                              void* d_out, int out_size, void* d_ws, size_t ws_size,
                              hipStream_t stream) {
    const float* x    = (const float*)d_in[0];
    const int*   src  = (const int*)d_in[1];
    const float* W_in = (const float*)d_in[3];
    const float* b_in = (const float*)d_in[4];
    const float* pos  = (const float*)d_in[5];
    const float* mW0  = (const float*)d_in[6];
    const float* mb0  = (const float*)d_in[7];
    const float* mW1  = (const float*)d_in[8];
    const float* mb1  = (const float*)d_in[9];
    const float* mW2  = (const float*)d_in[10];
    const float* mb2  = (const float*)d_in[11];
    const float* mW3  = (const float*)d_in[12];
    const float* mb3  = (const float*)d_in[13];
    const float* nW0  = (const float*)d_in[14];
    const float* nb0  = (const float*)d_in[15];
    const float* nW1  = (const float*)d_in[16];
    const float* nb1  = (const float*)d_in[17];
    const float* nW2  = (const float*)d_in[18];
    const float* nb2  = (const float*)d_in[19];
    const float* nW3  = (const float*)d_in[20];
    const float* nb3  = (const float*)d_in[21];
    const float* ln_g = (const float*)d_in[22];
    const float* ln_b = (const float*)d_in[23];
    const float* W_out= (const float*)d_in[24];
    const float* b_out= (const float*)d_in[25];

    char* ws = (char*)d_ws;
    bf16_t* hb  = (bf16_t*)ws;                      // 10,616,832 B (bf16 h; also x_embed)
    bf16_t* C2b = (bf16_t*)(ws + 10616832);         // 10,616,832 B
    bf16_t* SA  = (bf16_t*)(ws + 21233664);         // 10,616,832 B
    bf16_t* P   = (bf16_t*)(ws + 31850496);         // 10,616,832 B
    bf16_t* Q   = (bf16_t*)(ws + 42467328);         // 10,616,832 B (holds Q' = Q+mb0)
    bf16_t* Wp  = (bf16_t*)(ws + 53084160);         // 10 * 32,768 B (packed bf16)
    float*  bfix= (float*)(ws + 53411840);          // 512 B

    k_embed<<<20736, 256, 0, stream>>>(x, W_in, b_in, pos, hb);

    // packed slots: 0=mW0a 1=mW0b 2=mW1(32x32) 3=mW2(32x32) 4=nW0a(h) 5=Ft 6=nW1 7=nW2 8=nW3 9=nW0b(x)
    PackArgs pa;
    pa.s[0] = mW0;  pa.s[1] = mW0 + 16384; pa.s[2] = mW1; pa.s[3] = mW2;
    pa.s[4] = nW0;  pa.s[5] = nW1;  pa.s[6] = nW2;  pa.s[7] = nW3;  pa.s[8] = nW0 + 16384;
    k_pack_all<<<576, 256, 0, stream>>>(pa, Wp);
    k_fuse<<<64, 256, 0, stream>>>(mW3, nW0, Wp + 5 * 16384);
    k_bias<<<1, 128, 0, stream>>>(nb0, mb3, nW0, bfix);

    k_simple3<<<972, 256, 0, stream>>>(hb, Wp, bfix, mb0, C2b, P, Q);   // C2, P0, Q'0

    for (int s = 0; s < 16; s++) {
        k_edge<<<dim3(512, 27), 256, 0, stream>>>(P, Q, src, Wp, mb1, mb2, SA);
        k_node<<<1296, 256, 0, stream>>>(hb, SA, C2b, Wp, nb1, nb2, nb3, ln_g, ln_b, mb0, P, Q);
    }
    k_out<<<1458, 256, 0, stream>>>(hb, W_out, b_out, (float*)d_out);
}

// Round 11
// 2078.748 us; speedup vs baseline: 1.0135x; 1.0131x over previous
//
#include <hip/hip_runtime.h>
#include <hip/hip_bf16.h>

typedef __bf16 bf16_t;
typedef bf16_t bf16x8 __attribute__((ext_vector_type(8)));
typedef bf16_t bf16x4 __attribute__((ext_vector_type(4)));
typedef float  f32x4  __attribute__((ext_vector_type(4)));
typedef float  f32x16 __attribute__((ext_vector_type(16)));

#define NN   81
#define BB   512
#define BN   41472          // 512*81
#define EE   1620

// 4-bit XOR swizzle on the 16B granule index (node/prep kernels).
__device__ __forceinline__ int swz(int r, int k) {
    return (r << 7) + ((((k >> 3) ^ (r & 15)) << 3) | (k & 7));
}

// k_edge LDS layout: XOR-plane-major for the 64-row tile.
// element offset of (row r in 0..63, granule g = col>>3 in 0..15)
//   = g*512 + (r ^ (g&7))*8.
// - GEMM A-reads / wb writes: granule uniform per instruction, lm^c permutes
//   0..31 -> bank-balanced, and the XOR constant takes only 4 values ->
//   4 precomputed bases + immediate offsets (no per-read VALU; round-8/9's
//   measured ~6us VALU cut, which now translates at 72% occupancy).
// - Staging writes / agg reads: r fixed, g varies -> r^(g&7) spans 8 slots
//   (the 8-wrap minimum for 64x16B) -> round-9's measured conflict level.
__device__ __forceinline__ int pmje(int r, int g) {
    return (g << 9) + ((r ^ (g & 7)) << 3);
}

// 16x16x32 packed-weight offset (prep + node kernels)
__device__ __forceinline__ int wpack(int n, int k) {
    return ((n >> 6) << 13) + (((((k >> 5) << 2) + ((n >> 4) & 3))) << 9)
         + (((((k >> 3) & 3) << 4) + (n & 15)) << 3) + (k & 7);
}

// 32x32x16 packed-weight offset (edge kernel)
__device__ __forceinline__ int wpack32(int n, int k) {
    return ((((k >> 4) << 2) | (n >> 5)) << 9)
         + (((((k >> 3) & 1) << 5) | (n & 31)) << 3) + (k & 7);
}

// pack two f32 -> bf16x2, round-half-up: 2 adds + 1 v_perm
__device__ __forceinline__ unsigned pkbf(float lo, float hi) {
    unsigned a = __float_as_uint(lo) + 0x8000u;
    unsigned b = __float_as_uint(hi) + 0x8000u;
    return __builtin_amdgcn_perm(b, a, 0x07060302);
}

// truncating pack (1 v_perm) — intra-step activations only
__device__ __forceinline__ unsigned pkbf_t(float lo, float hi) {
    return __builtin_amdgcn_perm(__float_as_uint(hi), __float_as_uint(lo), 0x07060302);
}

__device__ __forceinline__ float bflo(unsigned d) { return __uint_as_float(d << 16); }
__device__ __forceinline__ float bfhi(unsigned d) { return __uint_as_float(d & 0xffff0000u); }

// relu(p+q) on packed bf16x2, all-f32 path (native v_max_f32)
__device__ __forceinline__ unsigned addrelu2(unsigned pd, unsigned qd) {
    float lo = fmaxf(bflo(pd) + bflo(qd), 0.f);
    float hi = fmaxf(bfhi(pd) + bfhi(qd), 0.f);
    return pkbf(lo, hi);
}

// ---------------- 16x16x32 GEMM (prep + node) ----------------
__device__ __forceinline__ void gemm128s(f32x4 (&acc)[4][4], const bf16_t* act,
                                         const bf16_t* __restrict__ Wp,
                                         int wm, int wn, int lane, int lrow, int q) {
    f32x4 z = {0.f, 0.f, 0.f, 0.f};
    #pragma unroll
    for (int i = 0; i < 4; i++)
        #pragma unroll
        for (int j = 0; j < 4; j++) acc[i][j] = z;
    const bf16_t* wbase = Wp + (wn << 13) + (lane << 3);
    #pragma unroll
    for (int k0 = 0; k0 < 128; k0 += 32) {
        bf16x8 af[4], wf[4];
        #pragma unroll
        for (int mt = 0; mt < 4; mt++)
            af[mt] = *(const bf16x8*)&act[swz(wm * 64 + mt * 16 + lrow, k0 + q * 8)];
        #pragma unroll
        for (int nt = 0; nt < 4; nt++)
            wf[nt] = *(const bf16x8*)(wbase + ((((k0 >> 5) << 2) + nt) << 9));
        #pragma unroll
        for (int nt = 0; nt < 4; nt++)
            #pragma unroll
            for (int mt = 0; mt < 4; mt++)
                acc[nt][mt] = __builtin_amdgcn_mfma_f32_16x16x32_bf16(wf[nt], af[mt], acc[nt][mt], 0, 0, 0);
    }
}

// ---------------- edge-kernel GEMM: wave tile M=64 rows x N=32 cols ----------------
// A-fragment for (kk,mt): granule G=2kk+h, rows mt*32+lm. Address =
// act + h*512 + (lm^((2(kk&3)+h))*8  [base, 4 variants]  + kk*1024 + mt*256 [imm].
__device__ __forceinline__ void gemm_e2(f32x16 (&acc)[2], const bf16_t* act,
                                        const bf16_t* __restrict__ W,
                                        const float* __restrict__ bias,
                                        int wid, int lane) {
    int lm = lane & 31, h = lane >> 5;
    #pragma unroll
    for (int gg = 0; gg < 4; gg++) {
        float4 b4 = *(const float4*)&bias[wid * 32 + 8 * gg + 4 * h];
        #pragma unroll
        for (int mt = 0; mt < 2; mt++) {
            acc[mt][4 * gg + 0] = b4.x; acc[mt][4 * gg + 1] = b4.y;
            acc[mt][4 * gg + 2] = b4.z; acc[mt][4 * gg + 3] = b4.w;
        }
    }
    const bf16_t* wl = W + (lane << 3);
    const bf16_t* al[4];
    #pragma unroll
    for (int j = 0; j < 4; j++)
        al[j] = act + (h << 9) + ((lm ^ ((2 * j + h) & 7)) << 3);
    #pragma unroll
    for (int kk = 0; kk < 8; kk++) {
        bf16x8 wf = *(const bf16x8*)(wl + (((kk << 2) + wid) << 9));
        #pragma unroll
        for (int mt = 0; mt < 2; mt++) {
            bf16x8 af = *(const bf16x8*)(al[kk & 3] + (kk << 10) + (mt << 8));
            acc[mt] = __builtin_amdgcn_mfma_f32_32x32x16_bf16(wf, af, acc[mt], 0, 0, 0);
        }
    }
}

// relu writeback: col nb=32wid+8gg+4h -> granule G=4wid+gg, elem 4h.
// 4 precomputed bases (XOR const = (4wid+gg)&7), mt via immediate.
__device__ __forceinline__ void wb_e2(bf16_t* act, f32x16 (&acc)[2], int wid, int lane) {
    int lm = lane & 31, h = lane >> 5;
    bf16_t* wb[4];
    #pragma unroll
    for (int gg = 0; gg < 4; gg++)
        wb[gg] = act + ((4 * wid + gg) << 9) + ((lm ^ ((4 * wid + gg) & 7)) << 3) + (h << 2);
    #pragma unroll
    for (int mt = 0; mt < 2; mt++)
        #pragma unroll
        for (int gg = 0; gg < 4; gg++) {
            uint2 u;
            u.x = pkbf_t(fmaxf(acc[mt][4 * gg + 0], 0.f), fmaxf(acc[mt][4 * gg + 1], 0.f));
            u.y = pkbf_t(fmaxf(acc[mt][4 * gg + 2], 0.f), fmaxf(acc[mt][4 * gg + 3], 0.f));
            *(uint2*)(wb[gg] + (mt << 8)) = u;
        }
}

// ---------------- node-kernel GEMM: wave tile 32(M) x 32(N) ----------------
__device__ __forceinline__ void gemm32s(f32x4 (&acc)[2][2], const bf16_t* act,
                                        const bf16_t* __restrict__ Wp,
                                        int wid, int lane, int lrow, int q, bool zero) {
    if (zero) {
        f32x4 z = {0.f, 0.f, 0.f, 0.f};
        acc[0][0] = z; acc[0][1] = z; acc[1][0] = z; acc[1][1] = z;
    }
    int wn = wid >> 1, ntb = (wid & 1) << 1;
    const bf16_t* wbase = Wp + (wn << 13) + (lane << 3);
    #pragma unroll
    for (int k0 = 0; k0 < 128; k0 += 32) {
        bf16x8 af[2], wf[2];
        af[0] = *(const bf16x8*)&act[swz(lrow, k0 + q * 8)];
        af[1] = *(const bf16x8*)&act[swz(16 + lrow, k0 + q * 8)];
        wf[0] = *(const bf16x8*)(wbase + ((((k0 >> 5) << 2) + ntb) << 9));
        wf[1] = *(const bf16x8*)(wbase + ((((k0 >> 5) << 2) + ntb + 1) << 9));
        #pragma unroll
        for (int nt = 0; nt < 2; nt++)
            #pragma unroll
            for (int mt = 0; mt < 2; mt++)
                acc[nt][mt] = __builtin_amdgcn_mfma_f32_16x16x32_bf16(wf[nt], af[mt], acc[nt][mt], 0, 0, 0);
    }
}

__device__ __forceinline__ void wb32(bf16_t* act, f32x4 (&acc)[2][2], const float* __restrict__ bias,
                                     int colb, int lrow, int q) {
    #pragma unroll
    for (int nt = 0; nt < 2; nt++) {
        int nb = colb + nt * 16 + q * 4;
        float4 b4 = *(const float4*)&bias[nb];
        #pragma unroll
        for (int mt = 0; mt < 2; mt++) {
            int m = mt * 16 + lrow;
            uint2 u;
            u.x = pkbf_t(fmaxf(acc[nt][mt][0] + b4.x, 0.f), fmaxf(acc[nt][mt][1] + b4.y, 0.f));
            u.y = pkbf_t(fmaxf(acc[nt][mt][2] + b4.z, 0.f), fmaxf(acc[nt][mt][3] + b4.w, 0.f));
            *(uint2*)&act[swz(m, nb)] = u;
        }
    }
}

// ---------------- prep kernels ----------------

__global__ __launch_bounds__(256) void k_embed(const float* __restrict__ x, const float* __restrict__ W_in,
                                               const float* __restrict__ b_in, const float* __restrict__ pos,
                                               bf16_t* __restrict__ hb) {
    int idx = blockIdx.x * 256 + threadIdx.x;   // < BN*128
    int row = idx >> 7, col = idx & 127;
    int n = row % NN;
    const float* xr = x + (size_t)row * 10;
    float s = b_in[col] + pos[n * 128 + col];
    #pragma unroll
    for (int k = 0; k < 10; k++) s += xr[k] * W_in[k * 128 + col];
    hb[idx] = (bf16_t)s;
}

struct PackArgs { const float* s[9]; };

__global__ __launch_bounds__(256) void k_pack_all(PackArgs pa, bf16_t* __restrict__ dst) {
    const int slot[9] = {0, 1, 2, 3, 4, 6, 7, 8, 9};
    int idx = blockIdx.x * 256 + threadIdx.x;   // < 9*16384
    int w = idx >> 14, r = idx & 16383;
    int n = r >> 7, k = r & 127;
    int po = (w == 2 || w == 3) ? wpack32(n, k) : wpack(n, k);   // edge weights use 32x32 layout
    dst[slot[w] * 16384 + po] = (bf16_t)pa.s[w][k * 128 + n];
}

__global__ __launch_bounds__(256) void k_fuse(const float* __restrict__ mW3, const float* __restrict__ nW0,
                                              bf16_t* __restrict__ Ft) {
    int idx = blockIdx.x * 256 + threadIdx.x;   // < 16384
    int n = idx >> 7, k = idx & 127;
    float s = 0.f;
    for (int j = 0; j < 128; j++) s += mW3[k * 128 + j] * nW0[(256 + j) * 128 + n];
    Ft[wpack(n, k)] = (bf16_t)s;
}

__global__ __launch_bounds__(128) void k_bias(const float* __restrict__ nb0, const float* __restrict__ mb3,
                                              const float* __restrict__ nW0, float* __restrict__ bfix) {
    int n = threadIdx.x;
    float s = 0.f;
    for (int j = 0; j < 128; j++) s += mb3[j] * nW0[(256 + j) * 128 + n];
    bfix[n] = nb0[n] + 20.f * s;
}

// one launch does C2 (bf16, bias=bfix), P (bf16), Q' (bf16, bias=mb0); input hb is bf16
__global__ __launch_bounds__(256, 2) void k_simple3(const bf16_t* __restrict__ in,
                                                    const bf16_t* __restrict__ Wp,
                                                    const float* __restrict__ bfix,
                                                    const float* __restrict__ mb0,
                                                    bf16_t* __restrict__ C2b,
                                                    bf16_t* __restrict__ Pd,
                                                    bf16_t* __restrict__ Qd) {
    __shared__ __align__(16) bf16_t act[16384];
    int tid = threadIdx.x;
    int sel = blockIdx.x / 324, blk = blockIdx.x - sel * 324;
    size_t i0 = (size_t)blk * 128;
    int lane = tid & 63, wid = tid >> 6;
    int wm = wid >> 1, wn = wid & 1, lrow = lane & 15, q = lane >> 4;

    for (int ch = tid; ch < 2048; ch += 256) {      // raw bf16 stage
        int r = ch >> 4, p = ch & 15;
        *(uint4*)&act[swz(r, p << 3)] = *(const uint4*)(in + (i0 + r) * 128 + (p << 3));
    }
    __syncthreads();
    const bf16_t* W = Wp + (sel == 0 ? 9 * 16384 : (sel == 1 ? 0 : 16384));
    f32x4 acc[4][4];
    gemm128s(acc, act, W, wm, wn, lane, lrow, q);
    bf16_t* dst = (sel == 0) ? C2b : ((sel == 1) ? Pd : Qd);
    #pragma unroll
    for (int nt = 0; nt < 4; nt++) {
        int nb = wn * 64 + nt * 16 + q * 4;
        float4 b4 = (sel == 0) ? *(const float4*)&bfix[nb]
                  : (sel == 2) ? *(const float4*)&mb0[nb]
                               : make_float4(0.f, 0.f, 0.f, 0.f);
        #pragma unroll
        for (int mt = 0; mt < 4; mt++) {
            int m = wm * 64 + mt * 16 + lrow;
            uint2 u;
            u.x = pkbf(acc[nt][mt][0] + b4.x, acc[nt][mt][1] + b4.y);
            u.y = pkbf(acc[nt][mt][2] + b4.z, acc[nt][mt][3] + b4.w);
            *(uint2*)(dst + (i0 + m) * 128 + nb) = u;
        }
    }
}

// ---------------- edge kernel: 32x32x16 MFMA, 60-edge tiles, 5 blocks/CU, affine LDS ----------------
// Grid (b=512, g=27): 1620 = 27*60 -> zero tail divergence. blockIdx.x=batch
// keeps per-XCD P/Q working set L2-resident (round-6: FETCH 42.7->10.7MB).
// Staging lane order = round 6's (16 consecutive lanes read 16 consecutive
// granules of one row -> coalesced; round-7 showed breaking this regresses).
__global__ __launch_bounds__(256, 5) void k_edge(const bf16_t* __restrict__ P, const bf16_t* __restrict__ Q,
                                                 const int* __restrict__ src, const bf16_t* __restrict__ Wp,
                                                 const float* __restrict__ mb1, const float* __restrict__ mb2,
                                                 bf16_t* __restrict__ SA) {
    __shared__ __align__(16) bf16_t act[8192];      // 16 granule-planes x 64 rows, 16KB
    int tid = threadIdx.x;
    int g = blockIdx.y, b = blockIdx.x;
    int e0 = g * 60, n0 = g * 3;
    int lane = tid & 63, w = tid >> 6;

    for (int ch = tid; ch < 1024; ch += 256) {
        int r = ch >> 4, p = ch & 15;
        uint4 o;
        if (r < 60) {
            int e = e0 + r;
            int sn = src[e];
            int dn = n0 + r / 20;
            uint4 pv = *(const uint4*)(P + (((size_t)b * NN + sn) << 7) + (p << 3));
            uint4 qv = *(const uint4*)(Q + (((size_t)b * NN + dn) << 7) + (p << 3));
            o.x = addrelu2(pv.x, qv.x);
            o.y = addrelu2(pv.y, qv.y);
            o.z = addrelu2(pv.z, qv.z);
            o.w = addrelu2(pv.w, qv.w);
        } else {
            o.x = 0u; o.y = 0u; o.z = 0u; o.w = 0u;
        }
        *(uint4*)&act[pmje(r, p)] = o;
    }
    __syncthreads();

    f32x16 acc[2];
    gemm_e2(acc, act, Wp + 2 * 16384, mb1, w, lane);     // act0 @ mW1 + mb1
    __syncthreads();
    wb_e2(act, acc, w, lane);                            // act1 = relu
    __syncthreads();
    gemm_e2(acc, act, Wp + 3 * 16384, mb2, w, lane);     // act1 @ mW2 + mb2
    __syncthreads();
    wb_e2(act, acc, w, lane);                            // act2 = relu
    __syncthreads();

    if (tid < 96) {                                      // 3 nodes x 32 threads
        int j = tid >> 5;
        int sub = tid & 31;
        int rr = sub >> 1;
        int half = sub & 1;
        float s0 = 0.f, s1 = 0.f, s2 = 0.f, s3 = 0.f, s4 = 0.f, s5 = 0.f, s6 = 0.f, s7 = 0.f;
        #pragma unroll
        for (int i = 0; i < 10; i++) {
            int m = 20 * j + half * 10 + i;
            bf16x8 v = *(const bf16x8*)&act[pmje(m, rr)];
            s0 += (float)v[0]; s1 += (float)v[1]; s2 += (float)v[2]; s3 += (float)v[3];
            s4 += (float)v[4]; s5 += (float)v[5]; s6 += (float)v[6]; s7 += (float)v[7];
        }
        s0 += __shfl_xor(s0, 1); s1 += __shfl_xor(s1, 1);
        s2 += __shfl_xor(s2, 1); s3 += __shfl_xor(s3, 1);
        s4 += __shfl_xor(s4, 1); s5 += __shfl_xor(s5, 1);
        s6 += __shfl_xor(s6, 1); s7 += __shfl_xor(s7, 1);
        if (half == 0) {
            uint4 o;
            o.x = pkbf(s0, s1); o.y = pkbf(s2, s3);
            o.z = pkbf(s4, s5); o.w = pkbf(s6, s7);
            *(uint4*)(SA + (((size_t)b * NN + n0 + j) << 7) + (rr << 3)) = o;
        }
    }
}

// ---------------- node kernel: bf16 h/C2, M=32, 4 waves x N=32 ----------------
__global__ __launch_bounds__(256, 6) void k_node(bf16_t* __restrict__ hb, const bf16_t* __restrict__ SA,
                                                 const bf16_t* __restrict__ C2b, const bf16_t* __restrict__ Wp,
                                                 const float* __restrict__ nb1, const float* __restrict__ nb2,
                                                 const float* __restrict__ nb3, const float* __restrict__ ln_g,
                                                 const float* __restrict__ ln_b, const float* __restrict__ mb0,
                                                 bf16_t* __restrict__ Pd, bf16_t* __restrict__ Qd) {
    __shared__ __align__(16) bf16_t act[4096];   // 32 rows x 128
    __shared__ __align__(16) bf16_t sab[4096];   // staged SA
    __shared__ float st[256];                    // 32 rows x 4 waves x {s1,s2}
    int tid = threadIdx.x;
    size_t i0 = (size_t)blockIdx.x * 32;
    int lane = tid & 63, wid = tid >> 6;
    int lrow = lane & 15, q = lane >> 4;
    int colb = wid * 32;

    // stage h (raw bf16 copy) and SA in one pass
    for (int ch = tid; ch < 1024; ch += 256) {
        if (ch < 512) {
            int r = ch >> 4, p = ch & 15;
            *(uint4*)&act[swz(r, p << 3)] = *(const uint4*)(hb + (i0 + r) * 128 + (p << 3));
        } else {
            int r = (ch - 512) >> 4, p = ch & 15;
            *(uint4*)&sab[swz(r, p << 3)] = *(const uint4*)(SA + (i0 + r) * 128 + (p << 3));
        }
    }
    __syncthreads();
    f32x4 acc[2][2];
    gemm32s(acc, act, Wp + 4 * 16384, wid, lane, lrow, q, true);     // h @ nW0a
    gemm32s(acc, sab, Wp + 5 * 16384, wid, lane, lrow, q, false);    // + SA @ Ft
    __syncthreads();
    // u0 = relu(acc + C2)
    #pragma unroll
    for (int nt = 0; nt < 2; nt++) {
        int nb = colb + nt * 16 + q * 4;
        #pragma unroll
        for (int mt = 0; mt < 2; mt++) {
            int m = mt * 16 + lrow;
            uint2 cv = *(const uint2*)(C2b + (i0 + m) * 128 + nb);
            uint2 u;
            u.x = pkbf_t(fmaxf(acc[nt][mt][0] + bflo(cv.x), 0.f), fmaxf(acc[nt][mt][1] + bfhi(cv.x), 0.f));
            u.y = pkbf_t(fmaxf(acc[nt][mt][2] + bflo(cv.y), 0.f), fmaxf(acc[nt][mt][3] + bfhi(cv.y), 0.f));
            *(uint2*)&act[swz(m, nb)] = u;
        }
    }
    __syncthreads();
    gemm32s(acc, act, Wp + 6 * 16384, wid, lane, lrow, q, true);     // nW1
    __syncthreads();
    wb32(act, acc, nb1, colb, lrow, q);
    __syncthreads();
    gemm32s(acc, act, Wp + 7 * 16384, wid, lane, lrow, q, true);     // nW2
    __syncthreads();
    wb32(act, acc, nb2, colb, lrow, q);
    __syncthreads();
    gemm32s(acc, act, Wp + 8 * 16384, wid, lane, lrow, q, true);     // nW3

    // residual v = acc + nb3 + h(bf16), LN stats
    float s1[2] = {0.f, 0.f}, s2[2] = {0.f, 0.f};
    #pragma unroll
    for (int nt = 0; nt < 2; nt++) {
        int nb = colb + nt * 16 + q * 4;
        float4 b4 = *(const float4*)&nb3[nb];
        #pragma unroll
        for (int mt = 0; mt < 2; mt++) {
            int m = mt * 16 + lrow;
            uint2 hv = *(const uint2*)(hb + (i0 + m) * 128 + nb);
            float v0 = acc[nt][mt][0] + b4.x + bflo(hv.x);
            float v1 = acc[nt][mt][1] + b4.y + bfhi(hv.x);
            float v2 = acc[nt][mt][2] + b4.z + bflo(hv.y);
            float v3 = acc[nt][mt][3] + b4.w + bfhi(hv.y);
            acc[nt][mt][0] = v0; acc[nt][mt][1] = v1;
            acc[nt][mt][2] = v2; acc[nt][mt][3] = v3;
            s1[mt] += v0 + v1 + v2 + v3;
            s2[mt] += v0 * v0 + v1 * v1 + v2 * v2 + v3 * v3;
        }
    }
    #pragma unroll
    for (int mt = 0; mt < 2; mt++) {
        float a = s1[mt], c = s2[mt];
        a += __shfl_xor(a, 16); c += __shfl_xor(c, 16);
        a += __shfl_xor(a, 32); c += __shfl_xor(c, 32);
        s1[mt] = a; s2[mt] = c;
    }
    if (q == 0) {
        #pragma unroll
        for (int mt = 0; mt < 2; mt++) {
            st[(mt * 16 + lrow) * 8 + wid * 2 + 0] = s1[mt];
            st[(mt * 16 + lrow) * 8 + wid * 2 + 1] = s2[mt];
        }
    }
    __syncthreads();
    float mu[2], rs[2];
    #pragma unroll
    for (int mt = 0; mt < 2; mt++) {
        int m = mt * 16 + lrow;
        float a = st[m * 8 + 0] + st[m * 8 + 2] + st[m * 8 + 4] + st[m * 8 + 6];
        float c = st[m * 8 + 1] + st[m * 8 + 3] + st[m * 8 + 5] + st[m * 8 + 7];
        a *= (1.f / 128.f); c *= (1.f / 128.f);
        mu[mt] = a;
        rs[mt] = rsqrtf(c - a * a + 1e-5f);
    }
    // LN apply -> hb (bf16 global) and act (same packed dwords)
    #pragma unroll
    for (int nt = 0; nt < 2; nt++) {
        int nb = colb + nt * 16 + q * 4;
        float4 g4 = *(const float4*)&ln_g[nb];
        float4 bb4 = *(const float4*)&ln_b[nb];
        #pragma unroll
        for (int mt = 0; mt < 2; mt++) {
            int m = mt * 16 + lrow;
            float o0 = (acc[nt][mt][0] - mu[mt]) * rs[mt] * g4.x + bb4.x;
            float o1 = (acc[nt][mt][1] - mu[mt]) * rs[mt] * g4.y + bb4.y;
            float o2 = (acc[nt][mt][2] - mu[mt]) * rs[mt] * g4.z + bb4.z;
            float o3 = (acc[nt][mt][3] - mu[mt]) * rs[mt] * g4.w + bb4.w;
            uint2 u;
            u.x = pkbf(o0, o1); u.y = pkbf(o2, o3);
            *(uint2*)(hb + (i0 + m) * 128 + nb) = u;
            *(uint2*)&act[swz(m, nb)] = u;
        }
    }
    __syncthreads();
    gemm32s(acc, act, Wp + 0 * 16384, wid, lane, lrow, q, true);     // mW0a -> P
    #pragma unroll
    for (int nt = 0; nt < 2; nt++) {
        int nb = colb + nt * 16 + q * 4;
        #pragma unroll
        for (int mt = 0; mt < 2; mt++) {
            int m = mt * 16 + lrow;
            uint2 u;
            u.x = pkbf(acc[nt][mt][0], acc[nt][mt][1]);
            u.y = pkbf(acc[nt][mt][2], acc[nt][mt][3]);
            *(uint2*)(Pd + (i0 + m) * 128 + nb) = u;
        }
    }
    gemm32s(acc, act, Wp + 1 * 16384, wid, lane, lrow, q, true);     // mW0b -> Q' (+mb0)
    #pragma unroll
    for (int nt = 0; nt < 2; nt++) {
        int nb = colb + nt * 16 + q * 4;
        float4 m4 = *(const float4*)&mb0[nb];
        #pragma unroll
        for (int mt = 0; mt < 2; mt++) {
            int m = mt * 16 + lrow;
            uint2 u;
            u.x = pkbf(acc[nt][mt][0] + m4.x, acc[nt][mt][1] + m4.y);
            u.y = pkbf(acc[nt][mt][2] + m4.z, acc[nt][mt][3] + m4.w);
            *(uint2*)(Qd + (i0 + m) * 128 + nb) = u;
        }
    }
}

__global__ __launch_bounds__(256) void k_out(const bf16_t* __restrict__ hb, const float* __restrict__ W_out,
                                             const float* __restrict__ b_out, float* __restrict__ out) {
    int idx = blockIdx.x * 256 + threadIdx.x;   // < BN*9
    int row = idx / 9, o = idx - row * 9;
    const bf16_t* hr = hb + (size_t)row * 128;
    float s = b_out[o];
    #pragma unroll 4
    for (int k8 = 0; k8 < 16; k8++) {
        bf16x8 v = *(const bf16x8*)(hr + k8 * 8);
        int kb = k8 * 8;
        #pragma unroll
        for (int j = 0; j < 8; j++) s += (float)v[j] * W_out[(kb + j) * 9 + o];
    }
    out[idx] = s;
}

extern "C" void kernel_launch(void* const* d_in, const int* in_sizes, int n_in,
                              void* d_out, int out_size, void* d_ws, size_t ws_size,
                              hipStream_t stream) {
    const float* x    = (const float*)d_in[0];
    const int*   src  = (const int*)d_in[1];
    const float* W_in = (const float*)d_in[3];
    const float* b_in = (const float*)d_in[4];
    const float* pos  = (const float*)d_in[5];
    const float* mW0  = (const float*)d_in[6];
    const float* mb0  = (const float*)d_in[7];
    const float* mW1  = (const float*)d_in[8];
    const float* mb1  = (const float*)d_in[9];
    const float* mW2  = (const float*)d_in[10];
    const float* mb2  = (const float*)d_in[11];
    const float* mW3  = (const float*)d_in[12];
    const float* mb3  = (const float*)d_in[13];
    const float* nW0  = (const float*)d_in[14];
    const float* nb0  = (const float*)d_in[15];
    const float* nW1  = (const float*)d_in[16];
    const float* nb1  = (const float*)d_in[17];
    const float* nW2  = (const float*)d_in[18];
    const float* nb2  = (const float*)d_in[19];
    const float* nW3  = (const float*)d_in[20];
    const float* nb3  = (const float*)d_in[21];
    const float* ln_g = (const float*)d_in[22];
    const float* ln_b = (const float*)d_in[23];
    const float* W_out= (const float*)d_in[24];
    const float* b_out= (const float*)d_in[25];

    char* ws = (char*)d_ws;
    bf16_t* hb  = (bf16_t*)ws;                      // 10,616,832 B (bf16 h; also x_embed)
    bf16_t* C2b = (bf16_t*)(ws + 10616832);         // 10,616,832 B
    bf16_t* SA  = (bf16_t*)(ws + 21233664);         // 10,616,832 B
    bf16_t* P   = (bf16_t*)(ws + 31850496);         // 10,616,832 B
    bf16_t* Q   = (bf16_t*)(ws + 42467328);         // 10,616,832 B (holds Q' = Q+mb0)
    bf16_t* Wp  = (bf16_t*)(ws + 53084160);         // 10 * 32,768 B (packed bf16)
    float*  bfix= (float*)(ws + 53411840);          // 512 B

    k_embed<<<20736, 256, 0, stream>>>(x, W_in, b_in, pos, hb);

    // packed slots: 0=mW0a 1=mW0b 2=mW1(32x32) 3=mW2(32x32) 4=nW0a(h) 5=Ft 6=nW1 7=nW2 8=nW3 9=nW0b(x)
    PackArgs pa;
    pa.s[0] = mW0;  pa.s[1] = mW0 + 16384; pa.s[2] = mW1; pa.s[3] = mW2;
    pa.s[4] = nW0;  pa.s[5] = nW1;  pa.s[6] = nW2;  pa.s[7] = nW3;  pa.s[8] = nW0 + 16384;
    k_pack_all<<<576, 256, 0, stream>>>(pa, Wp);
    k_fuse<<<64, 256, 0, stream>>>(mW3, nW0, Wp + 5 * 16384);
    k_bias<<<1, 128, 0, stream>>>(nb0, mb3, nW0, bfix);

    k_simple3<<<972, 256, 0, stream>>>(hb, Wp, bfix, mb0, C2b, P, Q);   // C2, P0, Q'0

    for (int s = 0; s < 16; s++) {
        k_edge<<<dim3(512, 27), 256, 0, stream>>>(P, Q, src, Wp, mb1, mb2, SA);
        k_node<<<1296, 256, 0, stream>>>(hb, SA, C2b, Wp, nb1, nb2, nb3, ln_g, ln_b, mb0, P, Q);
    }
    k_out<<<1458, 256, 0, stream>>>(hb, W_out, b_out, (float*)d_out);
}

// Round 12
// 1943.714 us; speedup vs baseline: 1.0839x; 1.0695x over previous
//
#include <hip/hip_runtime.h>
#include <hip/hip_bf16.h>

typedef __bf16 bf16_t;
typedef bf16_t bf16x8 __attribute__((ext_vector_type(8)));
typedef bf16_t bf16x4 __attribute__((ext_vector_type(4)));
typedef float  f32x4  __attribute__((ext_vector_type(4)));
typedef float  f32x16 __attribute__((ext_vector_type(16)));

#define NN   81
#define BB   512
#define BN   41472          // 512*81
#define EE   1620

// 4-bit XOR swizzle on the 16B granule index (node/prep kernels).
__device__ __forceinline__ int swz(int r, int k) {
    return (r << 7) + ((((k >> 3) ^ (r & 15)) << 3) | (k & 7));
}

// k_edge LDS layout: XOR-plane-major for the 64-row tile (round 11).
__device__ __forceinline__ int pmje(int r, int g) {
    return (g << 9) + ((r ^ (g & 7)) << 3);
}

// 16x16x32 packed-weight offset (prep + node kernels)
__device__ __forceinline__ int wpack(int n, int k) {
    return ((n >> 6) << 13) + (((((k >> 5) << 2) + ((n >> 4) & 3))) << 9)
         + (((((k >> 3) & 3) << 4) + (n & 15)) << 3) + (k & 7);
}

// 32x32x16 packed-weight offset (edge kernel)
__device__ __forceinline__ int wpack32(int n, int k) {
    return ((((k >> 4) << 2) | (n >> 5)) << 9)
         + (((((k >> 3) & 1) << 5) | (n & 31)) << 3) + (k & 7);
}

// pack two f32 -> bf16x2, round-half-up: 2 adds + 1 v_perm
__device__ __forceinline__ unsigned pkbf(float lo, float hi) {
    unsigned a = __float_as_uint(lo) + 0x8000u;
    unsigned b = __float_as_uint(hi) + 0x8000u;
    return __builtin_amdgcn_perm(b, a, 0x07060302);
}

// truncating pack (1 v_perm) — intra-step activations only
__device__ __forceinline__ unsigned pkbf_t(float lo, float hi) {
    return __builtin_amdgcn_perm(__float_as_uint(hi), __float_as_uint(lo), 0x07060302);
}

// packed bf16 relu in ONE op: for bf16 bit patterns, float relu == signed-i16
// max with 0 (positive bf16 sorts positive as i16; negative / -0 have the
// sign bit -> i16-negative -> clamped to 0). relu(trunc(x)) == trunc(relu(x)).
__device__ __forceinline__ unsigned relu2p(unsigned x) {
    unsigned r;
    asm("v_pk_max_i16 %0, %1, 0" : "=v"(r) : "v"(x));
    return r;
}

__device__ __forceinline__ float bflo(unsigned d) { return __uint_as_float(d << 16); }
__device__ __forceinline__ float bfhi(unsigned d) { return __uint_as_float(d & 0xffff0000u); }

// relu(p+q) on packed bf16x2: f32 add (exact on bf16 inputs), truncating
// pack, packed-i16 relu. 8 VALU ops vs 11 for the f32-relu + round path.
__device__ __forceinline__ unsigned addrelu2(unsigned pd, unsigned qd) {
    float lo = bflo(pd) + bflo(qd);
    float hi = bfhi(pd) + bfhi(qd);
    return relu2p(pkbf_t(lo, hi));
}

// ---------------- 16x16x32 GEMM (prep + node) ----------------
__device__ __forceinline__ void gemm128s(f32x4 (&acc)[4][4], const bf16_t* act,
                                         const bf16_t* __restrict__ Wp,
                                         int wm, int wn, int lane, int lrow, int q) {
    f32x4 z = {0.f, 0.f, 0.f, 0.f};
    #pragma unroll
    for (int i = 0; i < 4; i++)
        #pragma unroll
        for (int j = 0; j < 4; j++) acc[i][j] = z;
    const bf16_t* wbase = Wp + (wn << 13) + (lane << 3);
    #pragma unroll
    for (int k0 = 0; k0 < 128; k0 += 32) {
        bf16x8 af[4], wf[4];
        #pragma unroll
        for (int mt = 0; mt < 4; mt++)
            af[mt] = *(const bf16x8*)&act[swz(wm * 64 + mt * 16 + lrow, k0 + q * 8)];
        #pragma unroll
        for (int nt = 0; nt < 4; nt++)
            wf[nt] = *(const bf16x8*)(wbase + ((((k0 >> 5) << 2) + nt) << 9));
        #pragma unroll
        for (int nt = 0; nt < 4; nt++)
            #pragma unroll
            for (int mt = 0; mt < 4; mt++)
                acc[nt][mt] = __builtin_amdgcn_mfma_f32_16x16x32_bf16(wf[nt], af[mt], acc[nt][mt], 0, 0, 0);
    }
}

// ---------------- edge-kernel GEMM: wave tile M=64 rows x N=32 cols ----------------
__device__ __forceinline__ void gemm_e2(f32x16 (&acc)[2], const bf16_t* act,
                                        const bf16_t* __restrict__ W,
                                        const float* __restrict__ bias,
                                        int wid, int lane) {
    int lm = lane & 31, h = lane >> 5;
    #pragma unroll
    for (int gg = 0; gg < 4; gg++) {
        float4 b4 = *(const float4*)&bias[wid * 32 + 8 * gg + 4 * h];
        #pragma unroll
        for (int mt = 0; mt < 2; mt++) {
            acc[mt][4 * gg + 0] = b4.x; acc[mt][4 * gg + 1] = b4.y;
            acc[mt][4 * gg + 2] = b4.z; acc[mt][4 * gg + 3] = b4.w;
        }
    }
    const bf16_t* wl = W + (lane << 3);
    const bf16_t* al[4];
    #pragma unroll
    for (int j = 0; j < 4; j++)
        al[j] = act + (h << 9) + ((lm ^ ((2 * j + h) & 7)) << 3);
    #pragma unroll
    for (int kk = 0; kk < 8; kk++) {
        bf16x8 wf = *(const bf16x8*)(wl + (((kk << 2) + wid) << 9));
        #pragma unroll
        for (int mt = 0; mt < 2; mt++) {
            bf16x8 af = *(const bf16x8*)(al[kk & 3] + (kk << 10) + (mt << 8));
            acc[mt] = __builtin_amdgcn_mfma_f32_32x32x16_bf16(wf, af, acc[mt], 0, 0, 0);
        }
    }
}

// relu writeback: pack (perm) then packed-i16 relu — 4 ops/uint2 (was 6).
__device__ __forceinline__ void wb_e2(bf16_t* act, f32x16 (&acc)[2], int wid, int lane) {
    int lm = lane & 31, h = lane >> 5;
    bf16_t* wb[4];
    #pragma unroll
    for (int gg = 0; gg < 4; gg++)
        wb[gg] = act + ((4 * wid + gg) << 9) + ((lm ^ ((4 * wid + gg) & 7)) << 3) + (h << 2);
    #pragma unroll
    for (int mt = 0; mt < 2; mt++)
        #pragma unroll
        for (int gg = 0; gg < 4; gg++) {
            uint2 u;
            u.x = relu2p(pkbf_t(acc[mt][4 * gg + 0], acc[mt][4 * gg + 1]));
            u.y = relu2p(pkbf_t(acc[mt][4 * gg + 2], acc[mt][4 * gg + 3]));
            *(uint2*)(wb[gg] + (mt << 8)) = u;
        }
}

// ---------------- node-kernel GEMM: wave tile 32(M) x 32(N) ----------------
__device__ __forceinline__ void gemm32s(f32x4 (&acc)[2][2], const bf16_t* act,
                                        const bf16_t* __restrict__ Wp,
                                        int wid, int lane, int lrow, int q, bool zero) {
    if (zero) {
        f32x4 z = {0.f, 0.f, 0.f, 0.f};
        acc[0][0] = z; acc[0][1] = z; acc[1][0] = z; acc[1][1] = z;
    }
    int wn = wid >> 1, ntb = (wid & 1) << 1;
    const bf16_t* wbase = Wp + (wn << 13) + (lane << 3);
    #pragma unroll
    for (int k0 = 0; k0 < 128; k0 += 32) {
        bf16x8 af[2], wf[2];
        af[0] = *(const bf16x8*)&act[swz(lrow, k0 + q * 8)];
        af[1] = *(const bf16x8*)&act[swz(16 + lrow, k0 + q * 8)];
        wf[0] = *(const bf16x8*)(wbase + ((((k0 >> 5) << 2) + ntb) << 9));
        wf[1] = *(const bf16x8*)(wbase + ((((k0 >> 5) << 2) + ntb + 1) << 9));
        #pragma unroll
        for (int nt = 0; nt < 2; nt++)
            #pragma unroll
            for (int mt = 0; mt < 2; mt++)
                acc[nt][mt] = __builtin_amdgcn_mfma_f32_16x16x32_bf16(wf[nt], af[mt], acc[nt][mt], 0, 0, 0);
    }
}

__device__ __forceinline__ void wb32(bf16_t* act, f32x4 (&acc)[2][2], const float* __restrict__ bias,
                                     int colb, int lrow, int q) {
    #pragma unroll
    for (int nt = 0; nt < 2; nt++) {
        int nb = colb + nt * 16 + q * 4;
        float4 b4 = *(const float4*)&bias[nb];
        #pragma unroll
        for (int mt = 0; mt < 2; mt++) {
            int m = mt * 16 + lrow;
            uint2 u;
            u.x = relu2p(pkbf_t(acc[nt][mt][0] + b4.x, acc[nt][mt][1] + b4.y));
            u.y = relu2p(pkbf_t(acc[nt][mt][2] + b4.z, acc[nt][mt][3] + b4.w));
            *(uint2*)&act[swz(m, nb)] = u;
        }
    }
}

// ---------------- prep kernels ----------------

__global__ __launch_bounds__(256) void k_embed(const float* __restrict__ x, const float* __restrict__ W_in,
                                               const float* __restrict__ b_in, const float* __restrict__ pos,
                                               bf16_t* __restrict__ hb) {
    int idx = blockIdx.x * 256 + threadIdx.x;   // < BN*128
    int row = idx >> 7, col = idx & 127;
    int n = row % NN;
    const float* xr = x + (size_t)row * 10;
    float s = b_in[col] + pos[n * 128 + col];
    #pragma unroll
    for (int k = 0; k < 10; k++) s += xr[k] * W_in[k * 128 + col];
    hb[idx] = (bf16_t)s;
}

struct PackArgs { const float* s[9]; };

__global__ __launch_bounds__(256) void k_pack_all(PackArgs pa, bf16_t* __restrict__ dst) {
    const int slot[9] = {0, 1, 2, 3, 4, 6, 7, 8, 9};
    int idx = blockIdx.x * 256 + threadIdx.x;   // < 9*16384
    int w = idx >> 14, r = idx & 16383;
    int n = r >> 7, k = r & 127;
    int po = (w == 2 || w == 3) ? wpack32(n, k) : wpack(n, k);   // edge weights use 32x32 layout
    dst[slot[w] * 16384 + po] = (bf16_t)pa.s[w][k * 128 + n];
}

__global__ __launch_bounds__(256) void k_fuse(const float* __restrict__ mW3, const float* __restrict__ nW0,
                                              bf16_t* __restrict__ Ft) {
    int idx = blockIdx.x * 256 + threadIdx.x;   // < 16384
    int n = idx >> 7, k = idx & 127;
    float s = 0.f;
    for (int j = 0; j < 128; j++) s += mW3[k * 128 + j] * nW0[(256 + j) * 128 + n];
    Ft[wpack(n, k)] = (bf16_t)s;
}

__global__ __launch_bounds__(128) void k_bias(const float* __restrict__ nb0, const float* __restrict__ mb3,
                                              const float* __restrict__ nW0, float* __restrict__ bfix) {
    int n = threadIdx.x;
    float s = 0.f;
    for (int j = 0; j < 128; j++) s += mb3[j] * nW0[(256 + j) * 128 + n];
    bfix[n] = nb0[n] + 20.f * s;
}

// one launch does C2 (bf16, bias=bfix), P (bf16), Q' (bf16, bias=mb0); input hb is bf16
__global__ __launch_bounds__(256, 2) void k_simple3(const bf16_t* __restrict__ in,
                                                    const bf16_t* __restrict__ Wp,
                                                    const float* __restrict__ bfix,
                                                    const float* __restrict__ mb0,
                                                    bf16_t* __restrict__ C2b,
                                                    bf16_t* __restrict__ Pd,
                                                    bf16_t* __restrict__ Qd) {
    __shared__ __align__(16) bf16_t act[16384];
    int tid = threadIdx.x;
    int sel = blockIdx.x / 324, blk = blockIdx.x - sel * 324;
    size_t i0 = (size_t)blk * 128;
    int lane = tid & 63, wid = tid >> 6;
    int wm = wid >> 1, wn = wid & 1, lrow = lane & 15, q = lane >> 4;

    for (int ch = tid; ch < 2048; ch += 256) {      // raw bf16 stage
        int r = ch >> 4, p = ch & 15;
        *(uint4*)&act[swz(r, p << 3)] = *(const uint4*)(in + (i0 + r) * 128 + (p << 3));
    }
    __syncthreads();
    const bf16_t* W = Wp + (sel == 0 ? 9 * 16384 : (sel == 1 ? 0 : 16384));
    f32x4 acc[4][4];
    gemm128s(acc, act, W, wm, wn, lane, lrow, q);
    bf16_t* dst = (sel == 0) ? C2b : ((sel == 1) ? Pd : Qd);
    #pragma unroll
    for (int nt = 0; nt < 4; nt++) {
        int nb = wn * 64 + nt * 16 + q * 4;
        float4 b4 = (sel == 0) ? *(const float4*)&bfix[nb]
                  : (sel == 2) ? *(const float4*)&mb0[nb]
                               : make_float4(0.f, 0.f, 0.f, 0.f);
        #pragma unroll
        for (int mt = 0; mt < 4; mt++) {
            int m = wm * 64 + mt * 16 + lrow;
            uint2 u;
            u.x = pkbf(acc[nt][mt][0] + b4.x, acc[nt][mt][1] + b4.y);
            u.y = pkbf(acc[nt][mt][2] + b4.z, acc[nt][mt][3] + b4.w);
            *(uint2*)(dst + (i0 + m) * 128 + nb) = u;
        }
    }
}

// ---------------- edge kernel: 32x32x16 MFMA, 60-edge tiles, 5 blocks/CU, affine LDS ----------------
// Grid (b=512, g=27): 1620 = 27*60 -> zero tail divergence. blockIdx.x=batch
// keeps per-XCD P/Q working set L2-resident (round-6: FETCH 42.7->10.7MB).
// Staging lane order = round 6's (coalesced; round-7 showed breaking it regresses).
__global__ __launch_bounds__(256, 5) void k_edge(const bf16_t* __restrict__ P, const bf16_t* __restrict__ Q,
                                                 const int* __restrict__ src, const bf16_t* __restrict__ Wp,
                                                 const float* __restrict__ mb1, const float* __restrict__ mb2,
                                                 bf16_t* __restrict__ SA) {
    __shared__ __align__(16) bf16_t act[8192];      // 16 granule-planes x 64 rows, 16KB
    int tid = threadIdx.x;
    int g = blockIdx.y, b = blockIdx.x;
    int e0 = g * 60, n0 = g * 3;
    int lane = tid & 63, w = tid >> 6;

    for (int ch = tid; ch < 1024; ch += 256) {
        int r = ch >> 4, p = ch & 15;
        uint4 o;
        if (r < 60) {
            int e = e0 + r;
            int sn = src[e];
            int dn = n0 + r / 20;
            uint4 pv = *(const uint4*)(P + (((size_t)b * NN + sn) << 7) + (p << 3));
            uint4 qv = *(const uint4*)(Q + (((size_t)b * NN + dn) << 7) + (p << 3));
            o.x = addrelu2(pv.x, qv.x);
            o.y = addrelu2(pv.y, qv.y);
            o.z = addrelu2(pv.z, qv.z);
            o.w = addrelu2(pv.w, qv.w);
        } else {
            o.x = 0u; o.y = 0u; o.z = 0u; o.w = 0u;
        }
        *(uint4*)&act[pmje(r, p)] = o;
    }
    __syncthreads();

    f32x16 acc[2];
    gemm_e2(acc, act, Wp + 2 * 16384, mb1, w, lane);     // act0 @ mW1 + mb1
    __syncthreads();
    wb_e2(act, acc, w, lane);                            // act1 = relu
    __syncthreads();
    gemm_e2(acc, act, Wp + 3 * 16384, mb2, w, lane);     // act1 @ mW2 + mb2
    __syncthreads();
    wb_e2(act, acc, w, lane);                            // act2 = relu
    __syncthreads();

    if (tid < 96) {                                      // 3 nodes x 32 threads
        int j = tid >> 5;
        int sub = tid & 31;
        int rr = sub >> 1;
        int half = sub & 1;
        float s0 = 0.f, s1 = 0.f, s2 = 0.f, s3 = 0.f, s4 = 0.f, s5 = 0.f, s6 = 0.f, s7 = 0.f;
        #pragma unroll
        for (int i = 0; i < 10; i++) {
            int m = 20 * j + half * 10 + i;
            bf16x8 v = *(const bf16x8*)&act[pmje(m, rr)];
            s0 += (float)v[0]; s1 += (float)v[1]; s2 += (float)v[2]; s3 += (float)v[3];
            s4 += (float)v[4]; s5 += (float)v[5]; s6 += (float)v[6]; s7 += (float)v[7];
        }
        s0 += __shfl_xor(s0, 1); s1 += __shfl_xor(s1, 1);
        s2 += __shfl_xor(s2, 1); s3 += __shfl_xor(s3, 1);
        s4 += __shfl_xor(s4, 1); s5 += __shfl_xor(s5, 1);
        s6 += __shfl_xor(s6, 1); s7 += __shfl_xor(s7, 1);
        if (half == 0) {
            uint4 o;
            o.x = pkbf(s0, s1); o.y = pkbf(s2, s3);
            o.z = pkbf(s4, s5); o.w = pkbf(s6, s7);
            *(uint4*)(SA + (((size_t)b * NN + n0 + j) << 7) + (rr << 3)) = o;
        }
    }
}

// ---------------- node kernel: bf16 h/C2, M=32, 4 waves x N=32 ----------------
__global__ __launch_bounds__(256, 6) void k_node(bf16_t* __restrict__ hb, const bf16_t* __restrict__ SA,
                                                 const bf16_t* __restrict__ C2b, const bf16_t* __restrict__ Wp,
                                                 const float* __restrict__ nb1, const float* __restrict__ nb2,
                                                 const float* __restrict__ nb3, const float* __restrict__ ln_g,
                                                 const float* __restrict__ ln_b, const float* __restrict__ mb0,
                                                 bf16_t* __restrict__ Pd, bf16_t* __restrict__ Qd) {
    __shared__ __align__(16) bf16_t act[4096];   // 32 rows x 128
    __shared__ __align__(16) bf16_t sab[4096];   // staged SA
    __shared__ float st[256];                    // 32 rows x 4 waves x {s1,s2}
    int tid = threadIdx.x;
    size_t i0 = (size_t)blockIdx.x * 32;
    int lane = tid & 63, wid = tid >> 6;
    int lrow = lane & 15, q = lane >> 4;
    int colb = wid * 32;

    // stage h (raw bf16 copy) and SA in one pass
    for (int ch = tid; ch < 1024; ch += 256) {
        if (ch < 512) {
            int r = ch >> 4, p = ch & 15;
            *(uint4*)&act[swz(r, p << 3)] = *(const uint4*)(hb + (i0 + r) * 128 + (p << 3));
        } else {
            int r = (ch - 512) >> 4, p = ch & 15;
            *(uint4*)&sab[swz(r, p << 3)] = *(const uint4*)(SA + (i0 + r) * 128 + (p << 3));
        }
    }
    __syncthreads();
    f32x4 acc[2][2];
    gemm32s(acc, act, Wp + 4 * 16384, wid, lane, lrow, q, true);     // h @ nW0a
    gemm32s(acc, sab, Wp + 5 * 16384, wid, lane, lrow, q, false);    // + SA @ Ft
    __syncthreads();
    // u0 = relu(acc + C2)
    #pragma unroll
    for (int nt = 0; nt < 2; nt++) {
        int nb = colb + nt * 16 + q * 4;
        #pragma unroll
        for (int mt = 0; mt < 2; mt++) {
            int m = mt * 16 + lrow;
            uint2 cv = *(const uint2*)(C2b + (i0 + m) * 128 + nb);
            uint2 u;
            u.x = relu2p(pkbf_t(acc[nt][mt][0] + bflo(cv.x), acc[nt][mt][1] + bfhi(cv.x)));
            u.y = relu2p(pkbf_t(acc[nt][mt][2] + bflo(cv.y), acc[nt][mt][3] + bfhi(cv.y)));
            *(uint2*)&act[swz(m, nb)] = u;
        }
    }
    __syncthreads();
    gemm32s(acc, act, Wp + 6 * 16384, wid, lane, lrow, q, true);     // nW1
    __syncthreads();
    wb32(act, acc, nb1, colb, lrow, q);
    __syncthreads();
    gemm32s(acc, act, Wp + 7 * 16384, wid, lane, lrow, q, true);     // nW2
    __syncthreads();
    wb32(act, acc, nb2, colb, lrow, q);
    __syncthreads();
    gemm32s(acc, act, Wp + 8 * 16384, wid, lane, lrow, q, true);     // nW3

    // residual v = acc + nb3 + h(bf16), LN stats
    float s1[2] = {0.f, 0.f}, s2[2] = {0.f, 0.f};
    #pragma unroll
    for (int nt = 0; nt < 2; nt++) {
        int nb = colb + nt * 16 + q * 4;
        float4 b4 = *(const float4*)&nb3[nb];
        #pragma unroll
        for (int mt = 0; mt < 2; mt++) {
            int m = mt * 16 + lrow;
            uint2 hv = *(const uint2*)(hb + (i0 + m) * 128 + nb);
            float v0 = acc[nt][mt][0] + b4.x + bflo(hv.x);
            float v1 = acc[nt][mt][1] + b4.y + bfhi(hv.x);
            float v2 = acc[nt][mt][2] + b4.z + bflo(hv.y);
            float v3 = acc[nt][mt][3] + b4.w + bfhi(hv.y);
            acc[nt][mt][0] = v0; acc[nt][mt][1] = v1;
            acc[nt][mt][2] = v2; acc[nt][mt][3] = v3;
            s1[mt] += v0 + v1 + v2 + v3;
            s2[mt] += v0 * v0 + v1 * v1 + v2 * v2 + v3 * v3;
        }
    }
    #pragma unroll
    for (int mt = 0; mt < 2; mt++) {
        float a = s1[mt], c = s2[mt];
        a += __shfl_xor(a, 16); c += __shfl_xor(c, 16);
        a += __shfl_xor(a, 32); c += __shfl_xor(c, 32);
        s1[mt] = a; s2[mt] = c;
    }
    if (q == 0) {
        #pragma unroll
        for (int mt = 0; mt < 2; mt++) {
            st[(mt * 16 + lrow) * 8 + wid * 2 + 0] = s1[mt];
            st[(mt * 16 + lrow) * 8 + wid * 2 + 1] = s2[mt];
        }
    }
    __syncthreads();
    float mu[2], rs[2];
    #pragma unroll
    for (int mt = 0; mt < 2; mt++) {
        int m = mt * 16 + lrow;
        float a = st[m * 8 + 0] + st[m * 8 + 2] + st[m * 8 + 4] + st[m * 8 + 6];
        float c = st[m * 8 + 1] + st[m * 8 + 3] + st[m * 8 + 5] + st[m * 8 + 7];
        a *= (1.f / 128.f); c *= (1.f / 128.f);
        mu[mt] = a;
        rs[mt] = rsqrtf(c - a * a + 1e-5f);
    }
    // LN apply -> hb (bf16 global) and act (same packed dwords)
    #pragma unroll
    for (int nt = 0; nt < 2; nt++) {
        int nb = colb + nt * 16 + q * 4;
        float4 g4 = *(const float4*)&ln_g[nb];
        float4 bb4 = *(const float4*)&ln_b[nb];
        #pragma unroll
        for (int mt = 0; mt < 2; mt++) {
            int m = mt * 16 + lrow;
            float o0 = (acc[nt][mt][0] - mu[mt]) * rs[mt] * g4.x + bb4.x;
            float o1 = (acc[nt][mt][1] - mu[mt]) * rs[mt] * g4.y + bb4.y;
            float o2 = (acc[nt][mt][2] - mu[mt]) * rs[mt] * g4.z + bb4.z;
            float o3 = (acc[nt][mt][3] - mu[mt]) * rs[mt] * g4.w + bb4.w;
            uint2 u;
            u.x = pkbf(o0, o1); u.y = pkbf(o2, o3);
            *(uint2*)(hb + (i0 + m) * 128 + nb) = u;
            *(uint2*)&act[swz(m, nb)] = u;
        }
    }
    __syncthreads();
    gemm32s(acc, act, Wp + 0 * 16384, wid, lane, lrow, q, true);     // mW0a -> P
    #pragma unroll
    for (int nt = 0; nt < 2; nt++) {
        int nb = colb + nt * 16 + q * 4;
        #pragma unroll
        for (int mt = 0; mt < 2; mt++) {
            int m = mt * 16 + lrow;
            uint2 u;
            u.x = pkbf(acc[nt][mt][0], acc[nt][mt][1]);
            u.y = pkbf(acc[nt][mt][2], acc[nt][mt][3]);
            *(uint2*)(Pd + (i0 + m) * 128 + nb) = u;
        }
    }
    gemm32s(acc, act, Wp + 1 * 16384, wid, lane, lrow, q, true);     // mW0b -> Q' (+mb0)
    #pragma unroll
    for (int nt = 0; nt < 2; nt++) {
        int nb = colb + nt * 16 + q * 4;
        float4 m4 = *(const float4*)&mb0[nb];
        #pragma unroll
        for (int mt = 0; mt < 2; mt++) {
            int m = mt * 16 + lrow;
            uint2 u;
            u.x = pkbf(acc[nt][mt][0] + m4.x, acc[nt][mt][1] + m4.y);
            u.y = pkbf(acc[nt][mt][2] + m4.z, acc[nt][mt][3] + m4.w);
            *(uint2*)(Qd + (i0 + m) * 128 + nb) = u;
        }
    }
}

__global__ __launch_bounds__(256) void k_out(const bf16_t* __restrict__ hb, const float* __restrict__ W_out,
                                             const float* __restrict__ b_out, float* __restrict__ out) {
    int idx = blockIdx.x * 256 + threadIdx.x;   // < BN*9
    int row = idx / 9, o = idx - row * 9;
    const bf16_t* hr = hb + (size_t)row * 128;
    float s = b_out[o];
    #pragma unroll 4
    for (int k8 = 0; k8 < 16; k8++) {
        bf16x8 v = *(const bf16x8*)(hr + k8 * 8);
        int kb = k8 * 8;
        #pragma unroll
        for (int j = 0; j < 8; j++) s += (float)v[j] * W_out[(kb + j) * 9 + o];
    }
    out[idx] = s;
}

extern "C" void kernel_launch(void* const* d_in, const int* in_sizes, int n_in,
                              void* d_out, int out_size, void* d_ws, size_t ws_size,
                              hipStream_t stream) {
    const float* x    = (const float*)d_in[0];
    const int*   src  = (const int*)d_in[1];
    const float* W_in = (const float*)d_in[3];
    const float* b_in = (const float*)d_in[4];
    const float* pos  = (const float*)d_in[5];
    const float* mW0  = (const float*)d_in[6];
    const float* mb0  = (const float*)d_in[7];
    const float* mW1  = (const float*)d_in[8];
    const float* mb1  = (const float*)d_in[9];
    const float* mW2  = (const float*)d_in[10];
    const float* mb2  = (const float*)d_in[11];
    const float* mW3  = (const float*)d_in[12];
    const float* mb3  = (const float*)d_in[13];
    const float* nW0  = (const float*)d_in[14];
    const float* nb0  = (const float*)d_in[15];
    const float* nW1  = (const float*)d_in[16];
    const float* nb1  = (const float*)d_in[17];
    const float* nW2  = (const float*)d_in[18];
    const float* nb2  = (const float*)d_in[19];
    const float* nW3  = (const float*)d_in[20];
    const float* nb3  = (const float*)d_in[21];
    const float* ln_g = (const float*)d_in[22];
    const float* ln_b = (const float*)d_in[23];
    const float* W_out= (const float*)d_in[24];
    const float* b_out= (const float*)d_in[25];

    char* ws = (char*)d_ws;
    bf16_t* hb  = (bf16_t*)ws;                      // 10,616,832 B (bf16 h; also x_embed)
    bf16_t* C2b = (bf16_t*)(ws + 10616832);         // 10,616,832 B
    bf16_t* SA  = (bf16_t*)(ws + 21233664);         // 10,616,832 B
    bf16_t* P   = (bf16_t*)(ws + 31850496);         // 10,616,832 B
    bf16_t* Q   = (bf16_t*)(ws + 42467328);         // 10,616,832 B (holds Q' = Q+mb0)
    bf16_t* Wp  = (bf16_t*)(ws + 53084160);         // 10 * 32,768 B (packed bf16)
    float*  bfix= (float*)(ws + 53411840);          // 512 B

    k_embed<<<20736, 256, 0, stream>>>(x, W_in, b_in, pos, hb);

    // packed slots: 0=mW0a 1=mW0b 2=mW1(32x32) 3=mW2(32x32) 4=nW0a(h) 5=Ft 6=nW1 7=nW2 8=nW3 9=nW0b(x)
    PackArgs pa;
    pa.s[0] = mW0;  pa.s[1] = mW0 + 16384; pa.s[2] = mW1; pa.s[3] = mW2;
    pa.s[4] = nW0;  pa.s[5] = nW1;  pa.s[6] = nW2;  pa.s[7] = nW3;  pa.s[8] = nW0 + 16384;
    k_pack_all<<<576, 256, 0, stream>>>(pa, Wp);
    k_fuse<<<64, 256, 0, stream>>>(mW3, nW0, Wp + 5 * 16384);
    k_bias<<<1, 128, 0, stream>>>(nb0, mb3, nW0, bfix);

    k_simple3<<<972, 256, 0, stream>>>(hb, Wp, bfix, mb0, C2b, P, Q);   // C2, P0, Q'0

    for (int s = 0; s < 16; s++) {
        k_edge<<<dim3(512, 27), 256, 0, stream>>>(P, Q, src, Wp, mb1, mb2, SA);
        k_node<<<1296, 256, 0, stream>>>(hb, SA, C2b, Wp, nb1, nb2, nb3, ln_g, ln_b, mb0, P, Q);
    }
    k_out<<<1458, 256, 0, stream>>>(hb, W_out, b_out, (float*)d_out);
}